// Round 1
// baseline (4958.600 us; speedup 1.0000x reference)
//
#include <hip/hip_runtime.h>
#include <math.h>

// AdaAttN fp32 baseline.
// Pipeline: channel stats -> effective (norm-folded) weights -> per batch:
//   Q,K,V GEMMs -> logits GEMM (Q^T K) -> row softmax -> fused (V,A)->(M,E[V2]) GEMM + epilogue.

constexpr int B = 4;
constexpr int C = 512;    // Cqk == Cv == 512
constexpr int N = 4096;   // H*W
constexpr float EPSN = 1e-12f;  // added to std in channel norm
constexpr float EPSV = 1e-8f;   // added to clamped variance

// ---------------------------------------------------------------------------
// Per-channel mean / 1/(std+eps) over (B,H,W); ddof=1. which: 0=F_c_prev, 1=F_s_prev, 2=F_c
__global__ __launch_bounds__(256) void stats_kernel(
    const float* __restrict__ fcp, const float* __restrict__ fsp,
    const float* __restrict__ fc, float* __restrict__ stats)
{
    int c = blockIdx.x;
    int which = blockIdx.y;
    const float* src = (which == 0) ? fcp : ((which == 1) ? fsp : fc);
    float s = 0.f, s2 = 0.f;
    for (int b = 0; b < B; ++b) {
        const float4* p = reinterpret_cast<const float4*>(src + (size_t)(b * C + c) * N);
        for (int i = threadIdx.x; i < N / 4; i += 256) {
            float4 v = p[i];
            s  += v.x + v.y + v.z + v.w;
            s2 += v.x * v.x + v.y * v.y + v.z * v.z + v.w * v.w;
        }
    }
#pragma unroll
    for (int off = 32; off > 0; off >>= 1) {
        s  += __shfl_down(s, off);
        s2 += __shfl_down(s2, off);
    }
    __shared__ float w1[4], w2[4];
    if ((threadIdx.x & 63) == 0) { w1[threadIdx.x >> 6] = s; w2[threadIdx.x >> 6] = s2; }
    __syncthreads();
    if (threadIdx.x == 0) {
        float S  = w1[0] + w1[1] + w1[2] + w1[3];
        float S2 = w2[0] + w2[1] + w2[2] + w2[3];
        float n = (float)(B * N);
        float mean = S / n;
        float var = (S2 - S * S / n) / (n - 1.0f);
        var = fmaxf(var, 0.f);
        float inv = 1.0f / (sqrtf(var) + EPSN);
        stats[(which * C + c) * 2 + 0] = mean;
        stats[(which * C + c) * 2 + 1] = inv;
    }
}

// ---------------------------------------------------------------------------
// W'[o,c] = W[o,c]*inv[c];  b'[o] = b[o] - sum_c W'[o,c]*mean[c]
__global__ __launch_bounds__(256) void eff_weights_kernel(
    const float* __restrict__ Wf, const float* __restrict__ bf,
    const float* __restrict__ Wg, const float* __restrict__ bg,
    const float* __restrict__ stats,
    float* __restrict__ Wpf, float* __restrict__ bpf,
    float* __restrict__ Wpg, float* __restrict__ bpg)
{
    int o = blockIdx.x;
    int which = blockIdx.y;              // 0 -> f (stats block 0), 1 -> g (stats block 1)
    const float* W    = which ? Wg  : Wf;
    const float* bias = which ? bg  : bf;
    float* Wp         = which ? Wpg : Wpf;
    float* bp         = which ? bpg : bpf;
    const float* st = stats + which * C * 2;
    float corr = 0.f;
    for (int c = threadIdx.x; c < C; c += 256) {
        float wp = W[o * C + c] * st[c * 2 + 1];
        Wp[o * C + c] = wp;
        corr += wp * st[c * 2 + 0];
    }
#pragma unroll
    for (int off = 32; off > 0; off >>= 1) corr += __shfl_down(corr, off);
    __shared__ float wr[4];
    if ((threadIdx.x & 63) == 0) wr[threadIdx.x >> 6] = corr;
    __syncthreads();
    if (threadIdx.x == 0) bp[o] = bias[o] - (wr[0] + wr[1] + wr[2] + wr[3]);
}

// ---------------------------------------------------------------------------
// Y[o,n] = sum_c W[o,c] * X[c,n] + bias[o].  Tile 64x64, KC=16, 4x4 microtile.
__global__ __launch_bounds__(256) void gemm_wx(
    const float* __restrict__ W, const float* __restrict__ bias,
    const float* __restrict__ X, float* __restrict__ Y)
{
    __shared__ float Wt[16][65];
    __shared__ float Xt[16][64];
    int tx = threadIdx.x & 15, ty = threadIdx.x >> 4;
    int o0 = blockIdx.y * 64, n0 = blockIdx.x * 64;
    float acc[4][4] = {};
    for (int c0 = 0; c0 < C; c0 += 16) {
        {
            int r  = threadIdx.x >> 2;           // 0..63
            int kq = (threadIdx.x & 3) * 4;      // 0,4,8,12
            float4 w4 = *reinterpret_cast<const float4*>(&W[(size_t)(o0 + r) * C + c0 + kq]);
            Wt[kq + 0][r] = w4.x; Wt[kq + 1][r] = w4.y; Wt[kq + 2][r] = w4.z; Wt[kq + 3][r] = w4.w;
            int k = threadIdx.x >> 4;            // 0..15
            int j = (threadIdx.x & 15) * 4;      // 0..60
            *reinterpret_cast<float4*>(&Xt[k][j]) =
                *reinterpret_cast<const float4*>(&X[(size_t)(c0 + k) * N + n0 + j]);
        }
        __syncthreads();
#pragma unroll
        for (int k = 0; k < 16; ++k) {
            float a[4], bb[4];
#pragma unroll
            for (int i = 0; i < 4; ++i) a[i] = Wt[k][ty * 4 + i];
#pragma unroll
            for (int j = 0; j < 4; ++j) bb[j] = Xt[k][tx * 4 + j];
#pragma unroll
            for (int i = 0; i < 4; ++i)
#pragma unroll
                for (int j = 0; j < 4; ++j) acc[i][j] = fmaf(a[i], bb[j], acc[i][j]);
        }
        __syncthreads();
    }
#pragma unroll
    for (int i = 0; i < 4; ++i) {
        int o = o0 + ty * 4 + i;
        float bo = bias[o];
        float4 v = make_float4(acc[i][0] + bo, acc[i][1] + bo, acc[i][2] + bo, acc[i][3] + bo);
        *reinterpret_cast<float4*>(&Y[(size_t)o * N + n0 + tx * 4]) = v;
    }
}

// ---------------------------------------------------------------------------
// L[n,m] = sum_c Q[c,n]*K[c,m].  Tile 128x128, KC=8, 8x8 microtile.
__global__ __launch_bounds__(256) void gemm_qtk(
    const float* __restrict__ Q, const float* __restrict__ K, float* __restrict__ L)
{
    __shared__ float Qt[8][128];
    __shared__ float Kt[8][128];
    int tx = threadIdx.x & 15, ty = threadIdx.x >> 4;
    int n0 = blockIdx.y * 128, m0 = blockIdx.x * 128;
    float acc[8][8] = {};
    for (int c0 = 0; c0 < C; c0 += 8) {
        int k = threadIdx.x >> 5;           // 0..7
        int j = (threadIdx.x & 31) * 4;     // 0..124
        *reinterpret_cast<float4*>(&Qt[k][j]) =
            *reinterpret_cast<const float4*>(&Q[(size_t)(c0 + k) * N + n0 + j]);
        *reinterpret_cast<float4*>(&Kt[k][j]) =
            *reinterpret_cast<const float4*>(&K[(size_t)(c0 + k) * N + m0 + j]);
        __syncthreads();
#pragma unroll
        for (int k2 = 0; k2 < 8; ++k2) {
            float a[8], bb[8];
            *reinterpret_cast<float4*>(&a[0])  = *reinterpret_cast<float4*>(&Qt[k2][ty * 8]);
            *reinterpret_cast<float4*>(&a[4])  = *reinterpret_cast<float4*>(&Qt[k2][ty * 8 + 4]);
            *reinterpret_cast<float4*>(&bb[0]) = *reinterpret_cast<float4*>(&Kt[k2][tx * 8]);
            *reinterpret_cast<float4*>(&bb[4]) = *reinterpret_cast<float4*>(&Kt[k2][tx * 8 + 4]);
#pragma unroll
            for (int i = 0; i < 8; ++i)
#pragma unroll
                for (int j2 = 0; j2 < 8; ++j2) acc[i][j2] = fmaf(a[i], bb[j2], acc[i][j2]);
        }
        __syncthreads();
    }
#pragma unroll
    for (int i = 0; i < 8; ++i) {
        int n = n0 + ty * 8 + i;
        *reinterpret_cast<float4*>(&L[(size_t)n * N + m0 + tx * 8]) =
            make_float4(acc[i][0], acc[i][1], acc[i][2], acc[i][3]);
        *reinterpret_cast<float4*>(&L[(size_t)n * N + m0 + tx * 8 + 4]) =
            make_float4(acc[i][4], acc[i][5], acc[i][6], acc[i][7]);
    }
}

// ---------------------------------------------------------------------------
// Row softmax over m (in place), one block per row.
__global__ __launch_bounds__(256) void softmax_kernel(float* __restrict__ L)
{
    __shared__ float row[N];
    __shared__ float red[4];
    float* Lr = L + (size_t)blockIdx.x * N;
    float mx = -3.0e38f;
    for (int i = threadIdx.x; i < N / 4; i += 256) {
        float4 v = reinterpret_cast<const float4*>(Lr)[i];
        reinterpret_cast<float4*>(row)[i] = v;
        mx = fmaxf(fmaxf(mx, fmaxf(v.x, v.y)), fmaxf(v.z, v.w));
    }
#pragma unroll
    for (int off = 32; off > 0; off >>= 1) mx = fmaxf(mx, __shfl_xor(mx, off));
    if ((threadIdx.x & 63) == 0) red[threadIdx.x >> 6] = mx;
    __syncthreads();
    mx = fmaxf(fmaxf(red[0], red[1]), fmaxf(red[2], red[3]));
    __syncthreads();
    float s = 0.f;
    for (int i = threadIdx.x; i < N / 4; i += 256) {
        float4 v = reinterpret_cast<float4*>(row)[i];
        v.x = __expf(v.x - mx); v.y = __expf(v.y - mx);
        v.z = __expf(v.z - mx); v.w = __expf(v.w - mx);
        s += v.x + v.y + v.z + v.w;
        reinterpret_cast<float4*>(row)[i] = v;
    }
#pragma unroll
    for (int off = 32; off > 0; off >>= 1) s += __shfl_xor(s, off);
    if ((threadIdx.x & 63) == 0) red[threadIdx.x >> 6] = s;
    __syncthreads();
    float invs = 1.0f / (red[0] + red[1] + red[2] + red[3]);
    for (int i = threadIdx.x; i < N / 4; i += 256) {
        float4 v = reinterpret_cast<float4*>(row)[i];
        v.x *= invs; v.y *= invs; v.z *= invs; v.w *= invs;
        reinterpret_cast<float4*>(Lr)[i] = v;
    }
}

// ---------------------------------------------------------------------------
// M[v,n] = sum_m V[v,m]*A[n,m];  S2[v,n] = sum_m V[v,m]^2*A[n,m]; fused epilogue:
// out = sqrt(max(S2-M^2,0)+eps) * (F_c[v,n]-mean)*inv + M.  Tile 128x128, KC=8, 8x8.
__global__ __launch_bounds__(256) void gemm_av_epi(
    const float* __restrict__ Vm, const float* __restrict__ A,
    const float* __restrict__ Fc, const float* __restrict__ st3,
    float* __restrict__ out)
{
    __shared__ float Vt[8][128];
    __shared__ float V2t[8][128];
    __shared__ float At[8][128];
    int tx = threadIdx.x & 15, ty = threadIdx.x >> 4;
    int v0 = blockIdx.y * 128, n0 = blockIdx.x * 128;
    float accM[8][8] = {}, accS[8][8] = {};
    for (int m0 = 0; m0 < N; m0 += 8) {
        int r  = threadIdx.x >> 1;         // 0..127
        int kh = (threadIdx.x & 1) * 4;    // 0 or 4
        float4 v4 = *reinterpret_cast<const float4*>(&Vm[(size_t)(v0 + r) * N + m0 + kh]);
        Vt [kh + 0][r] = v4.x; Vt [kh + 1][r] = v4.y; Vt [kh + 2][r] = v4.z; Vt [kh + 3][r] = v4.w;
        V2t[kh + 0][r] = v4.x * v4.x; V2t[kh + 1][r] = v4.y * v4.y;
        V2t[kh + 2][r] = v4.z * v4.z; V2t[kh + 3][r] = v4.w * v4.w;
        float4 a4 = *reinterpret_cast<const float4*>(&A[(size_t)(n0 + r) * N + m0 + kh]);
        At[kh + 0][r] = a4.x; At[kh + 1][r] = a4.y; At[kh + 2][r] = a4.z; At[kh + 3][r] = a4.w;
        __syncthreads();
#pragma unroll
        for (int k2 = 0; k2 < 8; ++k2) {
            float av[8], aw[8], ba[8];
            *reinterpret_cast<float4*>(&av[0]) = *reinterpret_cast<float4*>(&Vt[k2][ty * 8]);
            *reinterpret_cast<float4*>(&av[4]) = *reinterpret_cast<float4*>(&Vt[k2][ty * 8 + 4]);
            *reinterpret_cast<float4*>(&aw[0]) = *reinterpret_cast<float4*>(&V2t[k2][ty * 8]);
            *reinterpret_cast<float4*>(&aw[4]) = *reinterpret_cast<float4*>(&V2t[k2][ty * 8 + 4]);
            *reinterpret_cast<float4*>(&ba[0]) = *reinterpret_cast<float4*>(&At[k2][tx * 8]);
            *reinterpret_cast<float4*>(&ba[4]) = *reinterpret_cast<float4*>(&At[k2][tx * 8 + 4]);
#pragma unroll
            for (int i = 0; i < 8; ++i)
#pragma unroll
                for (int j = 0; j < 8; ++j) {
                    accM[i][j] = fmaf(av[i], ba[j], accM[i][j]);
                    accS[i][j] = fmaf(aw[i], ba[j], accS[i][j]);
                }
        }
        __syncthreads();
    }
#pragma unroll
    for (int i = 0; i < 8; ++i) {
        int v = v0 + ty * 8 + i;
        float mean = st3[v * 2], inv = st3[v * 2 + 1];
#pragma unroll
        for (int jh = 0; jh < 2; ++jh) {
            int n = n0 + tx * 8 + jh * 4;
            float4 fc4 = *reinterpret_cast<const float4*>(&Fc[(size_t)v * N + n]);
            float f[4] = {fc4.x, fc4.y, fc4.z, fc4.w};
            float o[4];
#pragma unroll
            for (int q = 0; q < 4; ++q) {
                float m  = accM[i][jh * 4 + q];
                float var = accS[i][jh * 4 + q] - m * m;
                float sd = sqrtf(fmaxf(var, 0.f) + EPSV);
                o[q] = sd * ((f[q] - mean) * inv) + m;
            }
            *reinterpret_cast<float4*>(&out[(size_t)v * N + n]) =
                make_float4(o[0], o[1], o[2], o[3]);
        }
    }
}

// ---------------------------------------------------------------------------
extern "C" void kernel_launch(void* const* d_in, const int* in_sizes, int n_in,
                              void* d_out, int out_size, void* d_ws, size_t ws_size,
                              hipStream_t stream)
{
    const float* F_c      = (const float*)d_in[0];
    const float* F_s      = (const float*)d_in[1];
    const float* F_c_prev = (const float*)d_in[2];
    const float* F_s_prev = (const float*)d_in[3];
    const float* Wf = (const float*)d_in[4];
    const float* bf = (const float*)d_in[5];
    const float* Wg = (const float*)d_in[6];
    const float* bg = (const float*)d_in[7];
    const float* Wh = (const float*)d_in[8];
    const float* bh = (const float*)d_in[9];
    float* out = (float*)d_out;

    // workspace carve-up (floats)
    float* ws    = (float*)d_ws;
    float* stats = ws;                       // 3*512*2 = 3072
    float* Wpf   = stats + 3 * C * 2;
    float* bpf   = Wpf + C * C;
    float* Wpg   = bpf + C;
    float* bpg   = Wpg + C * C;
    float* Qb    = bpg + C;                  // C*N each
    float* Kb    = Qb + (size_t)C * N;
    float* Vb    = Kb + (size_t)C * N;
    float* Lb    = Vb + (size_t)C * N;       // N*N
    size_t need_floats = (size_t)(3 * C * 2) + 2 * ((size_t)C * C + C)
                       + 3 * (size_t)C * N + (size_t)N * N;
    if (ws_size < need_floats * sizeof(float)) return;  // insufficient scratch -> visible failure

    hipLaunchKernelGGL(stats_kernel, dim3(C, 3), dim3(256), 0, stream,
                       F_c_prev, F_s_prev, F_c, stats);
    hipLaunchKernelGGL(eff_weights_kernel, dim3(C, 2), dim3(256), 0, stream,
                       Wf, bf, Wg, bg, stats, Wpf, bpf, Wpg, bpg);

    for (int b = 0; b < B; ++b) {
        const float* Xq = F_c_prev + (size_t)b * C * N;
        const float* Xk = F_s_prev + (size_t)b * C * N;
        const float* Xv = F_s      + (size_t)b * C * N;
        hipLaunchKernelGGL(gemm_wx, dim3(N / 64, C / 64), dim3(256), 0, stream, Wpf, bpf, Xq, Qb);
        hipLaunchKernelGGL(gemm_wx, dim3(N / 64, C / 64), dim3(256), 0, stream, Wpg, bpg, Xk, Kb);
        hipLaunchKernelGGL(gemm_wx, dim3(N / 64, C / 64), dim3(256), 0, stream, Wh,  bh,  Xv, Vb);
        hipLaunchKernelGGL(gemm_qtk, dim3(N / 128, N / 128), dim3(256), 0, stream, Qb, Kb, Lb);
        hipLaunchKernelGGL(softmax_kernel, dim3(N), dim3(256), 0, stream, Lb);
        hipLaunchKernelGGL(gemm_av_epi, dim3(N / 128, C / 128), dim3(256), 0, stream,
                           Vb, Lb, F_c + (size_t)b * C * N, stats + 2 * C * 2,
                           out + (size_t)b * C * N);
    }
}

// Round 2
// 2275.396 us; speedup vs baseline: 2.1792x; 2.1792x over previous
//
#include <hip/hip_runtime.h>
#include <math.h>

// AdaAttN: fp32 convs/logits/softmax + bf16-MFMA attention-moment GEMM.
// Precision scheme: unnormalized bf16 softmax weights + exact fp32 row-sum
// renormalization; V rounded once to bf16 and its square split exactly into
// two bf16 (qh+ql) so var = S2 - M^2 is a genuine (>=0) variance.

constexpr int B = 4;
constexpr int C = 512;    // Cqk == Cv == 512
constexpr int N = 4096;   // H*W
constexpr int NC = 2048;  // n-chunk (keeps workspace <= proven 94 MB)
constexpr float EPSN = 1e-12f;
constexpr float EPSV = 1e-8f;

typedef __attribute__((ext_vector_type(4))) float f32x4;
typedef __attribute__((ext_vector_type(8))) short bf16x8;

static __device__ __forceinline__ unsigned short f2bf(float x) {
    union { float f; unsigned u; } c; c.f = x;
    unsigned r = c.u + 0x7FFFu + ((c.u >> 16) & 1u);   // RNE (inputs finite)
    return (unsigned short)(r >> 16);
}
static __device__ __forceinline__ float bf2f(unsigned short b) {
    union { unsigned u; float f; } c; c.u = ((unsigned)b) << 16;
    return c.f;
}

// ---------------------------------------------------------------------------
// Per-channel mean / 1/(std+eps) over (B,H,W); ddof=1. which: 0=F_c_prev, 1=F_s_prev, 2=F_c
__global__ __launch_bounds__(256) void stats_kernel(
    const float* __restrict__ fcp, const float* __restrict__ fsp,
    const float* __restrict__ fc, float* __restrict__ stats)
{
    int c = blockIdx.x;
    int which = blockIdx.y;
    const float* src = (which == 0) ? fcp : ((which == 1) ? fsp : fc);
    float s = 0.f, s2 = 0.f;
    for (int b = 0; b < B; ++b) {
        const float4* p = reinterpret_cast<const float4*>(src + (size_t)(b * C + c) * N);
        for (int i = threadIdx.x; i < N / 4; i += 256) {
            float4 v = p[i];
            s  += v.x + v.y + v.z + v.w;
            s2 += v.x * v.x + v.y * v.y + v.z * v.z + v.w * v.w;
        }
    }
#pragma unroll
    for (int off = 32; off > 0; off >>= 1) {
        s  += __shfl_down(s, off);
        s2 += __shfl_down(s2, off);
    }
    __shared__ float w1[4], w2[4];
    if ((threadIdx.x & 63) == 0) { w1[threadIdx.x >> 6] = s; w2[threadIdx.x >> 6] = s2; }
    __syncthreads();
    if (threadIdx.x == 0) {
        float S  = w1[0] + w1[1] + w1[2] + w1[3];
        float S2 = w2[0] + w2[1] + w2[2] + w2[3];
        float n = (float)(B * N);
        float mean = S / n;
        float var = (S2 - S * S / n) / (n - 1.0f);
        var = fmaxf(var, 0.f);
        float inv = 1.0f / (sqrtf(var) + EPSN);
        stats[(which * C + c) * 2 + 0] = mean;
        stats[(which * C + c) * 2 + 1] = inv;
    }
}

// ---------------------------------------------------------------------------
// W'[o,c] = W[o,c]*inv[c];  b'[o] = b[o] - sum_c W'[o,c]*mean[c]
__global__ __launch_bounds__(256) void eff_weights_kernel(
    const float* __restrict__ Wf, const float* __restrict__ bf,
    const float* __restrict__ Wg, const float* __restrict__ bg,
    const float* __restrict__ stats,
    float* __restrict__ Wpf, float* __restrict__ bpf,
    float* __restrict__ Wpg, float* __restrict__ bpg)
{
    int o = blockIdx.x;
    int which = blockIdx.y;
    const float* W    = which ? Wg  : Wf;
    const float* bias = which ? bg  : bf;
    float* Wp         = which ? Wpg : Wpf;
    float* bp         = which ? bpg : bpf;
    const float* st = stats + which * C * 2;
    float corr = 0.f;
    for (int c = threadIdx.x; c < C; c += 256) {
        float wp = W[o * C + c] * st[c * 2 + 1];
        Wp[o * C + c] = wp;
        corr += wp * st[c * 2 + 0];
    }
#pragma unroll
    for (int off = 32; off > 0; off >>= 1) corr += __shfl_down(corr, off);
    __shared__ float wr[4];
    if ((threadIdx.x & 63) == 0) wr[threadIdx.x >> 6] = corr;
    __syncthreads();
    if (threadIdx.x == 0) bp[o] = bias[o] - (wr[0] + wr[1] + wr[2] + wr[3]);
}

// ---------------------------------------------------------------------------
// Y[o,n] = sum_c W[o,c]*X[c,n] + bias[o].  fp32 out (Q,K).
__global__ __launch_bounds__(256) void gemm_wx(
    const float* __restrict__ W, const float* __restrict__ bias,
    const float* __restrict__ X, float* __restrict__ Y)
{
    __shared__ float Wt[16][65];
    __shared__ float Xt[16][64];
    int tx = threadIdx.x & 15, ty = threadIdx.x >> 4;
    int o0 = blockIdx.y * 64, n0 = blockIdx.x * 64;
    float acc[4][4] = {};
    for (int c0 = 0; c0 < C; c0 += 16) {
        {
            int r  = threadIdx.x >> 2;
            int kq = (threadIdx.x & 3) * 4;
            float4 w4 = *reinterpret_cast<const float4*>(&W[(size_t)(o0 + r) * C + c0 + kq]);
            Wt[kq + 0][r] = w4.x; Wt[kq + 1][r] = w4.y; Wt[kq + 2][r] = w4.z; Wt[kq + 3][r] = w4.w;
            int k = threadIdx.x >> 4;
            int j = (threadIdx.x & 15) * 4;
            *reinterpret_cast<float4*>(&Xt[k][j]) =
                *reinterpret_cast<const float4*>(&X[(size_t)(c0 + k) * N + n0 + j]);
        }
        __syncthreads();
#pragma unroll
        for (int k = 0; k < 16; ++k) {
            float a[4], bb[4];
#pragma unroll
            for (int i = 0; i < 4; ++i) a[i] = Wt[k][ty * 4 + i];
#pragma unroll
            for (int j = 0; j < 4; ++j) bb[j] = Xt[k][tx * 4 + j];
#pragma unroll
            for (int i = 0; i < 4; ++i)
#pragma unroll
                for (int j = 0; j < 4; ++j) acc[i][j] = fmaf(a[i], bb[j], acc[i][j]);
        }
        __syncthreads();
    }
#pragma unroll
    for (int i = 0; i < 4; ++i) {
        int o = o0 + ty * 4 + i;
        float bo = bias[o];
        float4 v = make_float4(acc[i][0] + bo, acc[i][1] + bo, acc[i][2] + bo, acc[i][3] + bo);
        *reinterpret_cast<float4*>(&Y[(size_t)o * N + n0 + tx * 4]) = v;
    }
}

// ---------------------------------------------------------------------------
// V-conv variant: writes T = [bf16(V); qh; ql] where qh+ql == bf16(V)^2 exactly.
__global__ __launch_bounds__(256) void gemm_wx_v(
    const float* __restrict__ W, const float* __restrict__ bias,
    const float* __restrict__ X, unsigned short* __restrict__ Tout)
{
    __shared__ float Wt[16][65];
    __shared__ float Xt[16][64];
    int tx = threadIdx.x & 15, ty = threadIdx.x >> 4;
    int o0 = blockIdx.y * 64, n0 = blockIdx.x * 64;
    float acc[4][4] = {};
    for (int c0 = 0; c0 < C; c0 += 16) {
        {
            int r  = threadIdx.x >> 2;
            int kq = (threadIdx.x & 3) * 4;
            float4 w4 = *reinterpret_cast<const float4*>(&W[(size_t)(o0 + r) * C + c0 + kq]);
            Wt[kq + 0][r] = w4.x; Wt[kq + 1][r] = w4.y; Wt[kq + 2][r] = w4.z; Wt[kq + 3][r] = w4.w;
            int k = threadIdx.x >> 4;
            int j = (threadIdx.x & 15) * 4;
            *reinterpret_cast<float4*>(&Xt[k][j]) =
                *reinterpret_cast<const float4*>(&X[(size_t)(c0 + k) * N + n0 + j]);
        }
        __syncthreads();
#pragma unroll
        for (int k = 0; k < 16; ++k) {
            float a[4], bb[4];
#pragma unroll
            for (int i = 0; i < 4; ++i) a[i] = Wt[k][ty * 4 + i];
#pragma unroll
            for (int j = 0; j < 4; ++j) bb[j] = Xt[k][tx * 4 + j];
#pragma unroll
            for (int i = 0; i < 4; ++i)
#pragma unroll
                for (int j = 0; j < 4; ++j) acc[i][j] = fmaf(a[i], bb[j], acc[i][j]);
        }
        __syncthreads();
    }
#pragma unroll
    for (int i = 0; i < 4; ++i) {
        int o = o0 + ty * 4 + i;
        float bo = bias[o];
        unsigned short hv[4], hq[4], hl[4];
#pragma unroll
        for (int q = 0; q < 4; ++q) {
            float vf = acc[i][q] + bo;
            unsigned short vb = f2bf(vf);
            float vhf = bf2f(vb);
            float sq  = vhf * vhf;                 // exact in fp32 (16-bit mantissa)
            unsigned short qb = f2bf(sq);
            float qlf = sq - bf2f(qb);             // exact remainder
            unsigned short lb = f2bf(qlf);         // exact (<=8 significant bits)
            hv[q] = vb; hq[q] = qb; hl[q] = lb;
        }
        size_t base = (size_t)o * N + n0 + tx * 4;
        *reinterpret_cast<ushort4*>(&Tout[base])                    = make_ushort4(hv[0], hv[1], hv[2], hv[3]);
        *reinterpret_cast<ushort4*>(&Tout[base + (size_t)C * N])    = make_ushort4(hq[0], hq[1], hq[2], hq[3]);
        *reinterpret_cast<ushort4*>(&Tout[base + (size_t)2 * C * N])= make_ushort4(hl[0], hl[1], hl[2], hl[3]);
    }
}

// ---------------------------------------------------------------------------
// L[nloc,m] = sum_c Q[c, nbase+nloc] * K[c, m].  128x128 tile, 8x8 microtile.
__global__ __launch_bounds__(256) void gemm_qtk(
    const float* __restrict__ Q, const float* __restrict__ K,
    float* __restrict__ L, int nbase)
{
    __shared__ float Qt[8][128];
    __shared__ float Kt[8][128];
    int tx = threadIdx.x & 15, ty = threadIdx.x >> 4;
    int nl0 = blockIdx.y * 128;          // local row in chunk
    int qn0 = nbase + nl0;               // global query column
    int m0 = blockIdx.x * 128;
    float acc[8][8] = {};
    for (int c0 = 0; c0 < C; c0 += 8) {
        int k = threadIdx.x >> 5;
        int j = (threadIdx.x & 31) * 4;
        *reinterpret_cast<float4*>(&Qt[k][j]) =
            *reinterpret_cast<const float4*>(&Q[(size_t)(c0 + k) * N + qn0 + j]);
        *reinterpret_cast<float4*>(&Kt[k][j]) =
            *reinterpret_cast<const float4*>(&K[(size_t)(c0 + k) * N + m0 + j]);
        __syncthreads();
#pragma unroll
        for (int k2 = 0; k2 < 8; ++k2) {
            float a[8], bb[8];
            *reinterpret_cast<float4*>(&a[0])  = *reinterpret_cast<float4*>(&Qt[k2][ty * 8]);
            *reinterpret_cast<float4*>(&a[4])  = *reinterpret_cast<float4*>(&Qt[k2][ty * 8 + 4]);
            *reinterpret_cast<float4*>(&bb[0]) = *reinterpret_cast<float4*>(&Kt[k2][tx * 8]);
            *reinterpret_cast<float4*>(&bb[4]) = *reinterpret_cast<float4*>(&Kt[k2][tx * 8 + 4]);
#pragma unroll
            for (int i = 0; i < 8; ++i)
#pragma unroll
                for (int j2 = 0; j2 < 8; ++j2) acc[i][j2] = fmaf(a[i], bb[j2], acc[i][j2]);
        }
        __syncthreads();
    }
#pragma unroll
    for (int i = 0; i < 8; ++i) {
        int n = nl0 + ty * 8 + i;
        *reinterpret_cast<float4*>(&L[(size_t)n * N + m0 + tx * 8]) =
            make_float4(acc[i][0], acc[i][1], acc[i][2], acc[i][3]);
        *reinterpret_cast<float4*>(&L[(size_t)n * N + m0 + tx * 8 + 4]) =
            make_float4(acc[i][4], acc[i][5], acc[i][6], acc[i][7]);
    }
}

// ---------------------------------------------------------------------------
// Row softmax -> UNNORMALIZED bf16 weights e~ = bf16(exp(l-max)) + exact fp32
// row sum of the rounded values; rowinv = 1/sum.
__global__ __launch_bounds__(256) void softmax_bf16(
    const float* __restrict__ L, unsigned short* __restrict__ E,
    float* __restrict__ rowinv)
{
    __shared__ float row[N];
    __shared__ float red[4];
    const float* Lr = L + (size_t)blockIdx.x * N;
    unsigned short* Er = E + (size_t)blockIdx.x * N;
    float mx = -3.0e38f;
    for (int i = threadIdx.x; i < N / 4; i += 256) {
        float4 v = reinterpret_cast<const float4*>(Lr)[i];
        reinterpret_cast<float4*>(row)[i] = v;
        mx = fmaxf(fmaxf(mx, fmaxf(v.x, v.y)), fmaxf(v.z, v.w));
    }
#pragma unroll
    for (int off = 32; off > 0; off >>= 1) mx = fmaxf(mx, __shfl_xor(mx, off));
    if ((threadIdx.x & 63) == 0) red[threadIdx.x >> 6] = mx;
    __syncthreads();
    mx = fmaxf(fmaxf(red[0], red[1]), fmaxf(red[2], red[3]));
    __syncthreads();
    float s = 0.f;
    for (int i = threadIdx.x; i < N / 4; i += 256) {
        float4 v = reinterpret_cast<float4*>(row)[i];
        unsigned short e0 = f2bf(__expf(v.x - mx));
        unsigned short e1 = f2bf(__expf(v.y - mx));
        unsigned short e2 = f2bf(__expf(v.z - mx));
        unsigned short e3 = f2bf(__expf(v.w - mx));
        s += bf2f(e0) + bf2f(e1) + bf2f(e2) + bf2f(e3);
        reinterpret_cast<ushort4*>(Er)[i] = make_ushort4(e0, e1, e2, e3);
    }
#pragma unroll
    for (int off = 32; off > 0; off >>= 1) s += __shfl_xor(s, off);
    if ((threadIdx.x & 63) == 0) red[threadIdx.x >> 6] = s;
    __syncthreads();
    if (threadIdx.x == 0)
        rowinv[blockIdx.x] = 1.0f / (red[0] + red[1] + red[2] + red[3]);
}

// ---------------------------------------------------------------------------
// P[v,n] = sum_m T[v,m] * E[n,m].  bf16 MFMA 16x16x32, 128x128 tile, BK=32,
// 4 waves x (64x64), global_load_lds width-16 staging (m97 pattern).
__global__ __launch_bounds__(256) void gemm_av_mfma(
    const unsigned short* __restrict__ T,   // [3C][N] bf16
    const unsigned short* __restrict__ E,   // [NC][N] bf16
    float* __restrict__ P)                  // [3C][NC] f32
{
    __shared__ unsigned short lA[128 * 32];
    __shared__ unsigned short lB[128 * 32];
    const int tid  = threadIdx.x;
    const int wave = tid >> 6, lane = tid & 63;
    const int v0 = blockIdx.y * 128;
    const int n0 = blockIdx.x * 128;
    const int wr = (wave >> 1) * 64, wc = (wave & 1) * 64;
    f32x4 acc[4][4] = {};

    const int s1 = tid,        r1 = s1 >> 2, c1 = (s1 & 3) * 8;
    const int s2 = tid + 256,  r2 = s2 >> 2, c2 = (s2 & 3) * 8;
    const int rowA = lane & 15;
    const int kk   = (lane >> 4) * 8;

    for (int k0 = 0; k0 < N; k0 += 32) {
        __syncthreads();   // previous compute done before overwriting LDS
        __builtin_amdgcn_global_load_lds(
            (const __attribute__((address_space(1))) void*)&T[(size_t)(v0 + r1) * N + k0 + c1],
            (__attribute__((address_space(3))) void*)&lA[wave * 512], 16, 0, 0);
        __builtin_amdgcn_global_load_lds(
            (const __attribute__((address_space(1))) void*)&T[(size_t)(v0 + r2) * N + k0 + c2],
            (__attribute__((address_space(3))) void*)&lA[2048 + wave * 512], 16, 0, 0);
        __builtin_amdgcn_global_load_lds(
            (const __attribute__((address_space(1))) void*)&E[(size_t)(n0 + r1) * N + k0 + c1],
            (__attribute__((address_space(3))) void*)&lB[wave * 512], 16, 0, 0);
        __builtin_amdgcn_global_load_lds(
            (const __attribute__((address_space(1))) void*)&E[(size_t)(n0 + r2) * N + k0 + c2],
            (__attribute__((address_space(3))) void*)&lB[2048 + wave * 512], 16, 0, 0);
        asm volatile("s_waitcnt vmcnt(0)" ::: "memory");
        __syncthreads();

        bf16x8 af[4], bfv[4];
#pragma unroll
        for (int f = 0; f < 4; ++f) {
            af[f]  = *reinterpret_cast<const bf16x8*>(&lA[(wr + f * 16 + rowA) * 32 + kk]);
            bfv[f] = *reinterpret_cast<const bf16x8*>(&lB[(wc + f * 16 + rowA) * 32 + kk]);
        }
#pragma unroll
        for (int fm = 0; fm < 4; ++fm)
#pragma unroll
            for (int fn = 0; fn < 4; ++fn)
                acc[fm][fn] = __builtin_amdgcn_mfma_f32_16x16x32_bf16(
                    af[fm], bfv[fn], acc[fm][fn], 0, 0, 0);
    }

    const int colD = lane & 15, rowD = (lane >> 4) * 4;
#pragma unroll
    for (int fm = 0; fm < 4; ++fm)
#pragma unroll
        for (int fn = 0; fn < 4; ++fn) {
            int col = n0 + wc + fn * 16 + colD;
            int row = v0 + wr + fm * 16 + rowD;
#pragma unroll
            for (int r = 0; r < 4; ++r)
                P[(size_t)(row + r) * NC + col] = acc[fm][fn][r];
        }
}

// ---------------------------------------------------------------------------
// out[v, nbase+n] = sqrt(max(S2-M^2,0)+eps) * (Fc-mean)*inv + M
// with M = P[v,n]*rowinv[n], S2 = (P[C+v,n]+P[2C+v,n])*rowinv[n].
__global__ __launch_bounds__(256) void av_epilogue(
    const float* __restrict__ P, const float* __restrict__ rowinv,
    const float* __restrict__ Fc, const float* __restrict__ st3,
    float* __restrict__ out, int nbase)
{
    int idx = blockIdx.x * 256 + threadIdx.x;      // over C*NC/4
    int v = idx >> 9;                              // / (NC/4)
    int n = (idx & 511) * 4;
    float4 pm = *reinterpret_cast<const float4*>(&P[(size_t)v * NC + n]);
    float4 ph = *reinterpret_cast<const float4*>(&P[(size_t)(C + v) * NC + n]);
    float4 pl = *reinterpret_cast<const float4*>(&P[(size_t)(2 * C + v) * NC + n]);
    float4 ri = *reinterpret_cast<const float4*>(&rowinv[n]);
    float mean = st3[v * 2], inv = st3[v * 2 + 1];
    float4 fc = *reinterpret_cast<const float4*>(&Fc[(size_t)v * N + nbase + n]);
    float o[4];
    float pmv[4] = {pm.x, pm.y, pm.z, pm.w};
    float phv[4] = {ph.x, ph.y, ph.z, ph.w};
    float plv[4] = {pl.x, pl.y, pl.z, pl.w};
    float riv[4] = {ri.x, ri.y, ri.z, ri.w};
    float fcv[4] = {fc.x, fc.y, fc.z, fc.w};
#pragma unroll
    for (int q = 0; q < 4; ++q) {
        float M  = pmv[q] * riv[q];
        float S2 = (phv[q] + plv[q]) * riv[q];
        float var = fmaxf(S2 - M * M, 0.f) + EPSV;
        o[q] = sqrtf(var) * ((fcv[q] - mean) * inv) + M;
    }
    *reinterpret_cast<float4*>(&out[(size_t)v * N + nbase + n]) =
        make_float4(o[0], o[1], o[2], o[3]);
}

// ---------------------------------------------------------------------------
extern "C" void kernel_launch(void* const* d_in, const int* in_sizes, int n_in,
                              void* d_out, int out_size, void* d_ws, size_t ws_size,
                              hipStream_t stream)
{
    const float* F_c      = (const float*)d_in[0];
    const float* F_s      = (const float*)d_in[1];
    const float* F_c_prev = (const float*)d_in[2];
    const float* F_s_prev = (const float*)d_in[3];
    const float* Wf = (const float*)d_in[4];
    const float* bf = (const float*)d_in[5];
    const float* Wg = (const float*)d_in[6];
    const float* bg = (const float*)d_in[7];
    const float* Wh = (const float*)d_in[8];
    const float* bh = (const float*)d_in[9];
    float* out = (float*)d_out;

    // workspace carve-up (float units; every region 16B-aligned)
    float* ws    = (float*)d_ws;
    float* stats = ws;                                   // 3*C*2
    float* Wpf   = stats + 3 * C * 2;                    // C*C
    float* bpf   = Wpf + C * C;                          // C
    float* Wpg   = bpf + C;                              // C*C
    float* bpg   = Wpg + C * C;                          // C
    float* Qb    = bpg + C;                              // C*N
    float* Kb    = Qb + (size_t)C * N;                   // C*N
    unsigned short* Tb = (unsigned short*)(Kb + (size_t)C * N);  // 3C*N bf16
    float* Lb    = (float*)(Tb + (size_t)3 * C * N);     // NC*N f32 (logits)
    float* Pb    = Lb;                                   // overlay: P (3C*NC) on dead L
    unsigned short* Eb = (unsigned short*)(Lb + (size_t)NC * N);  // NC*N bf16
    float* rinv  = (float*)(Eb + (size_t)NC * N);        // NC

    size_t need_floats = (size_t)(3 * C * 2) + 2 * ((size_t)C * C + C)
                       + 2 * (size_t)C * N                 // Q,K
                       + ((size_t)3 * C * N) / 2           // T (bf16)
                       + (size_t)NC * N                    // L/P
                       + ((size_t)NC * N) / 2              // E (bf16)
                       + NC;                               // rowinv
    if (ws_size < need_floats * sizeof(float)) return;

    hipLaunchKernelGGL(stats_kernel, dim3(C, 3), dim3(256), 0, stream,
                       F_c_prev, F_s_prev, F_c, stats);
    hipLaunchKernelGGL(eff_weights_kernel, dim3(C, 2), dim3(256), 0, stream,
                       Wf, bf, Wg, bg, stats, Wpf, bpf, Wpg, bpg);

    for (int b = 0; b < B; ++b) {
        const float* Xq = F_c_prev + (size_t)b * C * N;
        const float* Xk = F_s_prev + (size_t)b * C * N;
        const float* Xv = F_s      + (size_t)b * C * N;
        hipLaunchKernelGGL(gemm_wx,   dim3(N / 64, C / 64), dim3(256), 0, stream, Wpf, bpf, Xq, Qb);
        hipLaunchKernelGGL(gemm_wx,   dim3(N / 64, C / 64), dim3(256), 0, stream, Wpg, bpg, Xk, Kb);
        hipLaunchKernelGGL(gemm_wx_v, dim3(N / 64, C / 64), dim3(256), 0, stream, Wh, bh, Xv, Tb);
        for (int chunk = 0; chunk < N / NC; ++chunk) {
            int nbase = chunk * NC;
            hipLaunchKernelGGL(gemm_qtk, dim3(N / 128, NC / 128), dim3(256), 0, stream,
                               Qb, Kb, Lb, nbase);
            hipLaunchKernelGGL(softmax_bf16, dim3(NC), dim3(256), 0, stream, Lb, Eb, rinv);
            hipLaunchKernelGGL(gemm_av_mfma, dim3(NC / 128, 3 * C / 128), dim3(256), 0, stream,
                               Tb, Eb, Pb);
            hipLaunchKernelGGL(av_epilogue, dim3((C * NC / 4) / 256), dim3(256), 0, stream,
                               Pb, rinv, F_c + (size_t)b * C * N, stats + 2 * C * 2,
                               out + (size_t)b * C * N, nbase);
        }
    }
}

// Round 3
// 1768.241 us; speedup vs baseline: 2.8043x; 1.2868x over previous
//
#include <hip/hip_runtime.h>
#include <math.h>

// AdaAttN — all three GEMM stages on bf16 MFMA with exact two-term bf16 splits:
//   convs: Y = [Wh;Wl;Wh] . [Xh;Xh;Xl]   (K=1536, fp32-accurate)
//   logits: L = [Qh;Ql;Qh] . [Kh;Kh;Kl]  (K=1536, fp32-accurate)
//   moments: P = [V;qh;ql] . E~          (unnormalized bf16 softmax weights,
//                                         exact fp32 row-sum renormalization)

constexpr int B = 4;
constexpr int C = 512;     // Cqk == Cv == 512
constexpr int N = 4096;    // H*W
constexpr int NC = 2048;   // n-chunk
constexpr int C2 = 2 * C;  // split row length
constexpr int KS = 3 * C;  // split-GEMM depth
constexpr float EPSN = 1e-12f;
constexpr float EPSV = 1e-8f;

typedef __attribute__((ext_vector_type(4))) float f32x4;
typedef __attribute__((ext_vector_type(8))) short bf16x8;

static __device__ __forceinline__ unsigned short f2bf(float x) {
    union { float f; unsigned u; } c; c.f = x;
    unsigned r = c.u + 0x7FFFu + ((c.u >> 16) & 1u);   // RNE (finite inputs)
    return (unsigned short)(r >> 16);
}
static __device__ __forceinline__ float bf2f(unsigned short b) {
    union { unsigned u; float f; } c; c.u = ((unsigned)b) << 16;
    return c.f;
}

// ---------------------------------------------------------------------------
__global__ __launch_bounds__(256) void stats_kernel(
    const float* __restrict__ fcp, const float* __restrict__ fsp,
    const float* __restrict__ fc, float* __restrict__ stats)
{
    int c = blockIdx.x;
    int which = blockIdx.y;
    const float* src = (which == 0) ? fcp : ((which == 1) ? fsp : fc);
    float s = 0.f, s2 = 0.f;
    for (int b = 0; b < B; ++b) {
        const float4* p = reinterpret_cast<const float4*>(src + (size_t)(b * C + c) * N);
        for (int i = threadIdx.x; i < N / 4; i += 256) {
            float4 v = p[i];
            s  += v.x + v.y + v.z + v.w;
            s2 += v.x * v.x + v.y * v.y + v.z * v.z + v.w * v.w;
        }
    }
#pragma unroll
    for (int off = 32; off > 0; off >>= 1) {
        s  += __shfl_down(s, off);
        s2 += __shfl_down(s2, off);
    }
    __shared__ float w1[4], w2[4];
    if ((threadIdx.x & 63) == 0) { w1[threadIdx.x >> 6] = s; w2[threadIdx.x >> 6] = s2; }
    __syncthreads();
    if (threadIdx.x == 0) {
        float S  = w1[0] + w1[1] + w1[2] + w1[3];
        float S2 = w2[0] + w2[1] + w2[2] + w2[3];
        float n = (float)(B * N);
        float mean = S / n;
        float var = (S2 - S * S / n) / (n - 1.0f);
        var = fmaxf(var, 0.f);
        float inv = 1.0f / (sqrtf(var) + EPSN);
        stats[(which * C + c) * 2 + 0] = mean;
        stats[(which * C + c) * 2 + 1] = inv;
    }
}

// ---------------------------------------------------------------------------
// which 0: f (norm-folded, stats seg 0) / 1: g (seg 1) / 2: h (identity).
// Emits split weights Ws[o][0..C)=h, [C..2C)=l and effective bias.
__global__ __launch_bounds__(256) void eff_weights_split(
    const float* __restrict__ Wf, const float* __restrict__ bf_,
    const float* __restrict__ Wg, const float* __restrict__ bg_,
    const float* __restrict__ Wh, const float* __restrict__ bh_,
    const float* __restrict__ stats,
    unsigned short* __restrict__ Wsf, unsigned short* __restrict__ Wsg,
    unsigned short* __restrict__ Wsh,
    float* __restrict__ bpf, float* __restrict__ bpg, float* __restrict__ bph)
{
    int o = blockIdx.x;
    int which = blockIdx.y;
    const float* W    = (which == 0) ? Wf  : (which == 1) ? Wg  : Wh;
    const float* bias = (which == 0) ? bf_ : (which == 1) ? bg_ : bh_;
    unsigned short* Ws = (which == 0) ? Wsf : (which == 1) ? Wsg : Wsh;
    float* bp          = (which == 0) ? bpf : (which == 1) ? bpg : bph;
    float corr = 0.f;
    for (int c = threadIdx.x; c < C; c += 256) {
        float wp;
        if (which < 2) {
            const float* st = stats + which * C * 2;
            wp = W[o * C + c] * st[c * 2 + 1];
            corr += wp * st[c * 2 + 0];
        } else {
            wp = W[o * C + c];
        }
        unsigned short h = f2bf(wp);
        unsigned short l = f2bf(wp - bf2f(h));
        Ws[(size_t)o * C2 + c]     = h;
        Ws[(size_t)o * C2 + C + c] = l;
    }
#pragma unroll
    for (int off = 32; off > 0; off >>= 1) corr += __shfl_down(corr, off);
    __shared__ float wr[4];
    if ((threadIdx.x & 63) == 0) wr[threadIdx.x >> 6] = corr;
    __syncthreads();
    if (threadIdx.x == 0) bp[o] = bias[o] - (wr[0] + wr[1] + wr[2] + wr[3]);
}

// ---------------------------------------------------------------------------
// Transpose + exact bf16 split: F [C][N] f32 -> Xs [N][2C] bf16 (h | l).
__global__ __launch_bounds__(256) void in_split(
    const float* __restrict__ F, unsigned short* __restrict__ Xs)
{
    __shared__ float t[64][65];
    int n0 = blockIdx.x * 64, c0 = blockIdx.y * 64;
    int tx = threadIdx.x & 15, ty = threadIdx.x >> 4;
#pragma unroll
    for (int it = 0; it < 4; ++it) {
        int cl = ty + it * 16;
        float4 v = *reinterpret_cast<const float4*>(&F[(size_t)(c0 + cl) * N + n0 + tx * 4]);
        t[cl][tx * 4 + 0] = v.x; t[cl][tx * 4 + 1] = v.y;
        t[cl][tx * 4 + 2] = v.z; t[cl][tx * 4 + 3] = v.w;
    }
    __syncthreads();
#pragma unroll
    for (int it = 0; it < 4; ++it) {
        int nl = ty + it * 16;
        unsigned short h[4], l[4];
#pragma unroll
        for (int j = 0; j < 4; ++j) {
            float v = t[tx * 4 + j][nl];
            h[j] = f2bf(v);
            l[j] = f2bf(v - bf2f(h[j]));
        }
        size_t base = (size_t)(n0 + nl) * C2 + c0 + tx * 4;
        *reinterpret_cast<ushort4*>(&Xs[base])     = make_ushort4(h[0], h[1], h[2], h[3]);
        *reinterpret_cast<ushort4*>(&Xs[base + C]) = make_ushort4(l[0], l[1], l[2], l[3]);
    }
}

// ---------------------------------------------------------------------------
// V [C][N] f32 -> T [3C][N] bf16: rows [bf16(V); qh; ql], qh+ql == bf16(V)^2 exactly.
__global__ __launch_bounds__(256) void vsplit(
    const float* __restrict__ V, unsigned short* __restrict__ T)
{
    size_t i = (size_t)blockIdx.x * 256 + threadIdx.x;   // over C*N/4
    float4 v = reinterpret_cast<const float4*>(V)[i];
    float vals[4] = {v.x, v.y, v.z, v.w};
    unsigned short hv[4], hq[4], hl[4];
#pragma unroll
    for (int q = 0; q < 4; ++q) {
        unsigned short vb = f2bf(vals[q]);
        float vh = bf2f(vb);
        float sq = vh * vh;                 // exact in fp32
        unsigned short qb = f2bf(sq);
        float ql = sq - bf2f(qb);           // exact remainder
        hv[q] = vb; hq[q] = qb; hl[q] = f2bf(ql);
    }
    size_t base = i * 4;
    *reinterpret_cast<ushort4*>(&T[base])                     = make_ushort4(hv[0], hv[1], hv[2], hv[3]);
    *reinterpret_cast<ushort4*>(&T[base + (size_t)C * N])     = make_ushort4(hq[0], hq[1], hq[2], hq[3]);
    *reinterpret_cast<ushort4*>(&T[base + (size_t)2 * C * N]) = make_ushort4(hl[0], hl[1], hl[2], hl[3]);
}

// ---------------------------------------------------------------------------
// Split-GEMM conv: D[o,n] = sum_{k<1536} A[o,k]*Bm[n,k] + bias[o]
// A-stack = [Wh;Wl;Wh] via acol, B-stack = [Xh;Xh;Xl] via bcol.
// MODE 0: fp32 out Y[C][N] (V-conv). MODE 1: transposed split out Yt[N][2C] (Q/K).
template <int MODE>
__global__ __launch_bounds__(256) void conv_mfma(
    const unsigned short* __restrict__ Ws,   // [C][2C]
    const unsigned short* __restrict__ Xs,   // [N][2C]
    const float* __restrict__ bias,          // [C]
    float* __restrict__ Yf, unsigned short* __restrict__ Yt)
{
    __shared__ unsigned short lA[128 * 32];
    __shared__ unsigned short lB[128 * 32];
    const int tid  = threadIdx.x;
    const int wave = tid >> 6, lane = tid & 63;
    const int o0 = blockIdx.y * 128;
    const int n0 = blockIdx.x * 128;
    const int wr = (wave >> 1) * 64, wc = (wave & 1) * 64;
    f32x4 acc[4][4] = {};
    const int r1 = tid >> 2, c1 = (tid & 3) * 8;
    const int r2 = r1 + 64;
    const int rowA = lane & 15;
    const int kk   = (lane >> 4) * 8;

    for (int k0 = 0; k0 < KS; k0 += 32) {
        int acol = (k0 < 1024) ? k0 : k0 - 1024;
        int bcol = (k0 < 512)  ? k0 : k0 - 512;
        __syncthreads();
        __builtin_amdgcn_global_load_lds(
            (const __attribute__((address_space(1))) void*)&Ws[(size_t)(o0 + r1) * C2 + acol + c1],
            (__attribute__((address_space(3))) void*)&lA[wave * 512], 16, 0, 0);
        __builtin_amdgcn_global_load_lds(
            (const __attribute__((address_space(1))) void*)&Ws[(size_t)(o0 + r2) * C2 + acol + c1],
            (__attribute__((address_space(3))) void*)&lA[2048 + wave * 512], 16, 0, 0);
        __builtin_amdgcn_global_load_lds(
            (const __attribute__((address_space(1))) void*)&Xs[(size_t)(n0 + r1) * C2 + bcol + c1],
            (__attribute__((address_space(3))) void*)&lB[wave * 512], 16, 0, 0);
        __builtin_amdgcn_global_load_lds(
            (const __attribute__((address_space(1))) void*)&Xs[(size_t)(n0 + r2) * C2 + bcol + c1],
            (__attribute__((address_space(3))) void*)&lB[2048 + wave * 512], 16, 0, 0);
        asm volatile("s_waitcnt vmcnt(0)" ::: "memory");
        __syncthreads();

        bf16x8 af[4], bfv[4];
#pragma unroll
        for (int f = 0; f < 4; ++f) {
            af[f]  = *reinterpret_cast<const bf16x8*>(&lA[(wr + f * 16 + rowA) * 32 + kk]);
            bfv[f] = *reinterpret_cast<const bf16x8*>(&lB[(wc + f * 16 + rowA) * 32 + kk]);
        }
#pragma unroll
        for (int fm = 0; fm < 4; ++fm)
#pragma unroll
            for (int fn = 0; fn < 4; ++fn)
                acc[fm][fn] = __builtin_amdgcn_mfma_f32_16x16x32_bf16(
                    af[fm], bfv[fn], acc[fm][fn], 0, 0, 0);
    }

    const int colD = lane & 15, rowD = (lane >> 4) * 4;
#pragma unroll
    for (int fm = 0; fm < 4; ++fm) {
        int ob = o0 + wr + fm * 16 + rowD;
        float4 b4 = *reinterpret_cast<const float4*>(&bias[ob]);
        float bv[4] = {b4.x, b4.y, b4.z, b4.w};
#pragma unroll
        for (int fn = 0; fn < 4; ++fn) {
            int n = n0 + wc + fn * 16 + colD;
            if (MODE == 0) {
#pragma unroll
                for (int r = 0; r < 4; ++r)
                    Yf[(size_t)(ob + r) * N + n] = acc[fm][fn][r] + bv[r];
            } else {
                unsigned short hh[4], ll[4];
#pragma unroll
                for (int r = 0; r < 4; ++r) {
                    float val = acc[fm][fn][r] + bv[r];
                    hh[r] = f2bf(val);
                    ll[r] = f2bf(val - bf2f(hh[r]));
                }
                size_t base = (size_t)n * C2 + ob;
                *reinterpret_cast<ushort4*>(&Yt[base])     = make_ushort4(hh[0], hh[1], hh[2], hh[3]);
                *reinterpret_cast<ushort4*>(&Yt[base + C]) = make_ushort4(ll[0], ll[1], ll[2], ll[3]);
            }
        }
    }
}

// ---------------------------------------------------------------------------
// Logits: L[nl,m] = sum_{k<1536} Qstack[nbase+nl,k] * Kstack[m,k]  (fp32 out).
__global__ __launch_bounds__(256) void gemm_qtk_mfma(
    const unsigned short* __restrict__ Qs,   // [N][2C]
    const unsigned short* __restrict__ Ks,   // [N][2C]
    float* __restrict__ L, int nbase)
{
    __shared__ unsigned short lA[128 * 32];
    __shared__ unsigned short lB[128 * 32];
    const int tid  = threadIdx.x;
    const int wave = tid >> 6, lane = tid & 63;
    const int nl0 = blockIdx.y * 128;
    const int qn0 = nbase + nl0;
    const int m0  = blockIdx.x * 128;
    const int wr = (wave >> 1) * 64, wc = (wave & 1) * 64;
    f32x4 acc[4][4] = {};
    const int r1 = tid >> 2, c1 = (tid & 3) * 8;
    const int r2 = r1 + 64;
    const int rowA = lane & 15;
    const int kk   = (lane >> 4) * 8;

    for (int k0 = 0; k0 < KS; k0 += 32) {
        int acol = (k0 < 1024) ? k0 : k0 - 1024;   // [Qh;Ql;Qh]
        int bcol = (k0 < 512)  ? k0 : k0 - 512;    // [Kh;Kh;Kl]
        __syncthreads();
        __builtin_amdgcn_global_load_lds(
            (const __attribute__((address_space(1))) void*)&Qs[(size_t)(qn0 + r1) * C2 + acol + c1],
            (__attribute__((address_space(3))) void*)&lA[wave * 512], 16, 0, 0);
        __builtin_amdgcn_global_load_lds(
            (const __attribute__((address_space(1))) void*)&Qs[(size_t)(qn0 + r2) * C2 + acol + c1],
            (__attribute__((address_space(3))) void*)&lA[2048 + wave * 512], 16, 0, 0);
        __builtin_amdgcn_global_load_lds(
            (const __attribute__((address_space(1))) void*)&Ks[(size_t)(m0 + r1) * C2 + bcol + c1],
            (__attribute__((address_space(3))) void*)&lB[wave * 512], 16, 0, 0);
        __builtin_amdgcn_global_load_lds(
            (const __attribute__((address_space(1))) void*)&Ks[(size_t)(m0 + r2) * C2 + bcol + c1],
            (__attribute__((address_space(3))) void*)&lB[2048 + wave * 512], 16, 0, 0);
        asm volatile("s_waitcnt vmcnt(0)" ::: "memory");
        __syncthreads();

        bf16x8 af[4], bfv[4];
#pragma unroll
        for (int f = 0; f < 4; ++f) {
            af[f]  = *reinterpret_cast<const bf16x8*>(&lA[(wr + f * 16 + rowA) * 32 + kk]);
            bfv[f] = *reinterpret_cast<const bf16x8*>(&lB[(wc + f * 16 + rowA) * 32 + kk]);
        }
#pragma unroll
        for (int fm = 0; fm < 4; ++fm)
#pragma unroll
            for (int fn = 0; fn < 4; ++fn)
                acc[fm][fn] = __builtin_amdgcn_mfma_f32_16x16x32_bf16(
                    af[fm], bfv[fn], acc[fm][fn], 0, 0, 0);
    }

    const int colD = lane & 15, rowD = (lane >> 4) * 4;
#pragma unroll
    for (int fm = 0; fm < 4; ++fm)
#pragma unroll
        for (int fn = 0; fn < 4; ++fn) {
            int col = m0 + wc + fn * 16 + colD;
            int row = nl0 + wr + fm * 16 + rowD;
#pragma unroll
            for (int r = 0; r < 4; ++r)
                L[(size_t)(row + r) * N + col] = acc[fm][fn][r];
        }
}

// ---------------------------------------------------------------------------
// Row softmax -> unnormalized bf16 weights + exact fp32 row-sum inverse.
__global__ __launch_bounds__(256) void softmax_bf16(
    const float* __restrict__ L, unsigned short* __restrict__ E,
    float* __restrict__ rowinv)
{
    __shared__ float row[N];
    __shared__ float red[4];
    const float* Lr = L + (size_t)blockIdx.x * N;
    unsigned short* Er = E + (size_t)blockIdx.x * N;
    float mx = -3.0e38f;
    for (int i = threadIdx.x; i < N / 4; i += 256) {
        float4 v = reinterpret_cast<const float4*>(Lr)[i];
        reinterpret_cast<float4*>(row)[i] = v;
        mx = fmaxf(fmaxf(mx, fmaxf(v.x, v.y)), fmaxf(v.z, v.w));
    }
#pragma unroll
    for (int off = 32; off > 0; off >>= 1) mx = fmaxf(mx, __shfl_xor(mx, off));
    if ((threadIdx.x & 63) == 0) red[threadIdx.x >> 6] = mx;
    __syncthreads();
    mx = fmaxf(fmaxf(red[0], red[1]), fmaxf(red[2], red[3]));
    __syncthreads();
    float s = 0.f;
    for (int i = threadIdx.x; i < N / 4; i += 256) {
        float4 v = reinterpret_cast<float4*>(row)[i];
        unsigned short e0 = f2bf(__expf(v.x - mx));
        unsigned short e1 = f2bf(__expf(v.y - mx));
        unsigned short e2 = f2bf(__expf(v.z - mx));
        unsigned short e3 = f2bf(__expf(v.w - mx));
        s += bf2f(e0) + bf2f(e1) + bf2f(e2) + bf2f(e3);
        reinterpret_cast<ushort4*>(Er)[i] = make_ushort4(e0, e1, e2, e3);
    }
#pragma unroll
    for (int off = 32; off > 0; off >>= 1) s += __shfl_xor(s, off);
    if ((threadIdx.x & 63) == 0) red[threadIdx.x >> 6] = s;
    __syncthreads();
    if (threadIdx.x == 0)
        rowinv[blockIdx.x] = 1.0f / (red[0] + red[1] + red[2] + red[3]);
}

// ---------------------------------------------------------------------------
// P[v,n] = sum_m T[v,m] * E[n,m].
__global__ __launch_bounds__(256) void gemm_av_mfma(
    const unsigned short* __restrict__ T,   // [3C][N]
    const unsigned short* __restrict__ E,   // [NC][N]
    float* __restrict__ P)                  // [3C][NC]
{
    __shared__ unsigned short lA[128 * 32];
    __shared__ unsigned short lB[128 * 32];
    const int tid  = threadIdx.x;
    const int wave = tid >> 6, lane = tid & 63;
    const int v0 = blockIdx.y * 128;
    const int n0 = blockIdx.x * 128;
    const int wr = (wave >> 1) * 64, wc = (wave & 1) * 64;
    f32x4 acc[4][4] = {};
    const int r1 = tid >> 2, c1 = (tid & 3) * 8;
    const int r2 = r1 + 64;
    const int rowA = lane & 15;
    const int kk   = (lane >> 4) * 8;

    for (int k0 = 0; k0 < N; k0 += 32) {
        __syncthreads();
        __builtin_amdgcn_global_load_lds(
            (const __attribute__((address_space(1))) void*)&T[(size_t)(v0 + r1) * N + k0 + c1],
            (__attribute__((address_space(3))) void*)&lA[wave * 512], 16, 0, 0);
        __builtin_amdgcn_global_load_lds(
            (const __attribute__((address_space(1))) void*)&T[(size_t)(v0 + r2) * N + k0 + c1],
            (__attribute__((address_space(3))) void*)&lA[2048 + wave * 512], 16, 0, 0);
        __builtin_amdgcn_global_load_lds(
            (const __attribute__((address_space(1))) void*)&E[(size_t)(n0 + r1) * N + k0 + c1],
            (__attribute__((address_space(3))) void*)&lB[wave * 512], 16, 0, 0);
        __builtin_amdgcn_global_load_lds(
            (const __attribute__((address_space(1))) void*)&E[(size_t)(n0 + r2) * N + k0 + c1],
            (__attribute__((address_space(3))) void*)&lB[2048 + wave * 512], 16, 0, 0);
        asm volatile("s_waitcnt vmcnt(0)" ::: "memory");
        __syncthreads();

        bf16x8 af[4], bfv[4];
#pragma unroll
        for (int f = 0; f < 4; ++f) {
            af[f]  = *reinterpret_cast<const bf16x8*>(&lA[(wr + f * 16 + rowA) * 32 + kk]);
            bfv[f] = *reinterpret_cast<const bf16x8*>(&lB[(wc + f * 16 + rowA) * 32 + kk]);
        }
#pragma unroll
        for (int fm = 0; fm < 4; ++fm)
#pragma unroll
            for (int fn = 0; fn < 4; ++fn)
                acc[fm][fn] = __builtin_amdgcn_mfma_f32_16x16x32_bf16(
                    af[fm], bfv[fn], acc[fm][fn], 0, 0, 0);
    }

    const int colD = lane & 15, rowD = (lane >> 4) * 4;
#pragma unroll
    for (int fm = 0; fm < 4; ++fm)
#pragma unroll
        for (int fn = 0; fn < 4; ++fn) {
            int col = n0 + wc + fn * 16 + colD;
            int row = v0 + wr + fm * 16 + rowD;
#pragma unroll
            for (int r = 0; r < 4; ++r)
                P[(size_t)(row + r) * NC + col] = acc[fm][fn][r];
        }
}

// ---------------------------------------------------------------------------
__global__ __launch_bounds__(256) void av_epilogue(
    const float* __restrict__ P, const float* __restrict__ rowinv,
    const float* __restrict__ Fc, const float* __restrict__ st3,
    float* __restrict__ out, int nbase)
{
    int idx = blockIdx.x * 256 + threadIdx.x;      // over C*NC/4
    int v = idx >> 9;
    int n = (idx & 511) * 4;
    float4 pm = *reinterpret_cast<const float4*>(&P[(size_t)v * NC + n]);
    float4 ph = *reinterpret_cast<const float4*>(&P[(size_t)(C + v) * NC + n]);
    float4 pl = *reinterpret_cast<const float4*>(&P[(size_t)(2 * C + v) * NC + n]);
    float4 ri = *reinterpret_cast<const float4*>(&rowinv[n]);
    float mean = st3[v * 2], inv = st3[v * 2 + 1];
    float4 fc = *reinterpret_cast<const float4*>(&Fc[(size_t)v * N + nbase + n]);
    float pmv[4] = {pm.x, pm.y, pm.z, pm.w};
    float phv[4] = {ph.x, ph.y, ph.z, ph.w};
    float plv[4] = {pl.x, pl.y, pl.z, pl.w};
    float riv[4] = {ri.x, ri.y, ri.z, ri.w};
    float fcv[4] = {fc.x, fc.y, fc.z, fc.w};
    float o[4];
#pragma unroll
    for (int q = 0; q < 4; ++q) {
        float M  = pmv[q] * riv[q];
        float S2 = (phv[q] + plv[q]) * riv[q];
        float var = fmaxf(S2 - M * M, 0.f) + EPSV;
        o[q] = sqrtf(var) * ((fcv[q] - mean) * inv) + M;
    }
    *reinterpret_cast<float4*>(&out[(size_t)v * N + nbase + n]) =
        make_float4(o[0], o[1], o[2], o[3]);
}

// ---------------------------------------------------------------------------
extern "C" void kernel_launch(void* const* d_in, const int* in_sizes, int n_in,
                              void* d_out, int out_size, void* d_ws, size_t ws_size,
                              hipStream_t stream)
{
    const float* F_c      = (const float*)d_in[0];
    const float* F_s      = (const float*)d_in[1];
    const float* F_c_prev = (const float*)d_in[2];
    const float* F_s_prev = (const float*)d_in[3];
    const float* Wf = (const float*)d_in[4];
    const float* bf_ = (const float*)d_in[5];
    const float* Wg = (const float*)d_in[6];
    const float* bg_ = (const float*)d_in[7];
    const float* Wh = (const float*)d_in[8];
    const float* bh_ = (const float*)d_in[9];
    float* out = (float*)d_out;

    // byte-offset workspace carve-up, 256B aligned regions
    char* base = (char*)d_ws;
    size_t off = 0;
    auto alloc = [&](size_t bytes) { void* p = base + off; off = (off + bytes + 255) & ~(size_t)255; return p; };
    float* stats = (float*)alloc(3 * C * 2 * 4);
    float* bpf   = (float*)alloc(C * 4);
    float* bpg   = (float*)alloc(C * 4);
    float* bph   = (float*)alloc(C * 4);
    unsigned short* Wsf = (unsigned short*)alloc((size_t)C * C2 * 2);
    unsigned short* Wsg = (unsigned short*)alloc((size_t)C * C2 * 2);
    unsigned short* Wsh = (unsigned short*)alloc((size_t)C * C2 * 2);
    unsigned short* Qs  = (unsigned short*)alloc((size_t)N * C2 * 2);
    unsigned short* Ks  = (unsigned short*)alloc((size_t)N * C2 * 2);
    unsigned short* Tb  = (unsigned short*)alloc((size_t)3 * C * N * 2);
    float* Lb   = (float*)alloc((size_t)NC * N * 4);
    float* Pb   = Lb;                                       // overlay on dead L
    float* rinv = (float*)alloc(NC * 4);
    // union region U: [Xs | Vf32] vs [E]
    char* U = (char*)alloc((size_t)NC * N * 2);             // 16 MB = max use
    unsigned short* Xs = (unsigned short*)U;                // N*2C bf16 = 8 MB
    float* Vf          = (float*)(U + (size_t)N * C2 * 2);  // C*N f32 = 8 MB
    unsigned short* Eb = (unsigned short*)U;                // NC*N bf16 = 16 MB
    if (ws_size < off) return;  // insufficient scratch -> visible failure

    hipLaunchKernelGGL(stats_kernel, dim3(C, 3), dim3(256), 0, stream,
                       F_c_prev, F_s_prev, F_c, stats);
    hipLaunchKernelGGL(eff_weights_split, dim3(C, 3), dim3(256), 0, stream,
                       Wf, bf_, Wg, bg_, Wh, bh_, stats, Wsf, Wsg, Wsh, bpf, bpg, bph);

    for (int b = 0; b < B; ++b) {
        const float* Xq = F_c_prev + (size_t)b * C * N;
        const float* Xk = F_s_prev + (size_t)b * C * N;
        const float* Xv = F_s      + (size_t)b * C * N;

        hipLaunchKernelGGL(in_split, dim3(N / 64, C / 64), dim3(256), 0, stream, Xq, Xs);
        conv_mfma<1><<<dim3(N / 128, C / 128), 256, 0, stream>>>(Wsf, Xs, bpf, nullptr, Qs);
        hipLaunchKernelGGL(in_split, dim3(N / 64, C / 64), dim3(256), 0, stream, Xk, Xs);
        conv_mfma<1><<<dim3(N / 128, C / 128), 256, 0, stream>>>(Wsg, Xs, bpg, nullptr, Ks);
        hipLaunchKernelGGL(in_split, dim3(N / 64, C / 64), dim3(256), 0, stream, Xv, Xs);
        conv_mfma<0><<<dim3(N / 128, C / 128), 256, 0, stream>>>(Wsh, Xs, bph, Vf, nullptr);
        hipLaunchKernelGGL(vsplit, dim3(C * N / 4 / 256), dim3(256), 0, stream, Vf, Tb);

        for (int chunk = 0; chunk < N / NC; ++chunk) {
            int nbase = chunk * NC;
            hipLaunchKernelGGL(gemm_qtk_mfma, dim3(N / 128, NC / 128), dim3(256), 0, stream,
                               Qs, Ks, Lb, nbase);
            hipLaunchKernelGGL(softmax_bf16, dim3(NC), dim3(256), 0, stream, Lb, Eb, rinv);
            hipLaunchKernelGGL(gemm_av_mfma, dim3(NC / 128, 3 * C / 128), dim3(256), 0, stream,
                               Tb, Eb, Pb);
            hipLaunchKernelGGL(av_epilogue, dim3((C * NC / 4) / 256), dim3(256), 0, stream,
                               Pb, rinv, F_c + (size_t)b * C * N, stats + 2 * C * 2,
                               out + (size_t)b * C * N, nbase);
        }
    }
}

// Round 4
// 1210.324 us; speedup vs baseline: 4.0969x; 1.4610x over previous
//
#include <hip/hip_runtime.h>
#include <math.h>

// AdaAttN — all GEMMs on bf16 MFMA (16x16x32, 128^2 tile, m97 staging).
// Round 4: grid-filling round. Split-K AV GEMM (384 blocks), merged 3-way conv
// launch (384 blocks), merged in_split, V-split fused into conv epilogue.

constexpr int B = 4;
constexpr int C = 512;     // Cqk == Cv == 512
constexpr int N = 4096;    // H*W
constexpr int NC = 2048;   // n-chunk
constexpr int C2 = 2 * C;  // split row length
constexpr int KS = 3 * C;  // split-GEMM depth (convs & logits)
constexpr int HK = N / 2;  // AV split-K half depth
constexpr float EPSN = 1e-12f;
constexpr float EPSV = 1e-8f;

typedef __attribute__((ext_vector_type(4))) float f32x4;
typedef __attribute__((ext_vector_type(8))) short bf16x8;

static __device__ __forceinline__ unsigned short f2bf(float x) {
    union { float f; unsigned u; } c; c.f = x;
    unsigned r = c.u + 0x7FFFu + ((c.u >> 16) & 1u);   // RNE (finite inputs)
    return (unsigned short)(r >> 16);
}
static __device__ __forceinline__ float bf2f(unsigned short b) {
    union { unsigned u; float f; } c; c.u = ((unsigned)b) << 16;
    return c.f;
}

// ---------------------------------------------------------------------------
__global__ __launch_bounds__(256) void stats_kernel(
    const float* __restrict__ fcp, const float* __restrict__ fsp,
    const float* __restrict__ fc, float* __restrict__ stats)
{
    int c = blockIdx.x;
    int which = blockIdx.y;
    const float* src = (which == 0) ? fcp : ((which == 1) ? fsp : fc);
    float s = 0.f, s2 = 0.f;
    for (int b = 0; b < B; ++b) {
        const float4* p = reinterpret_cast<const float4*>(src + (size_t)(b * C + c) * N);
        for (int i = threadIdx.x; i < N / 4; i += 256) {
            float4 v = p[i];
            s  += v.x + v.y + v.z + v.w;
            s2 += v.x * v.x + v.y * v.y + v.z * v.z + v.w * v.w;
        }
    }
#pragma unroll
    for (int off = 32; off > 0; off >>= 1) {
        s  += __shfl_down(s, off);
        s2 += __shfl_down(s2, off);
    }
    __shared__ float w1[4], w2[4];
    if ((threadIdx.x & 63) == 0) { w1[threadIdx.x >> 6] = s; w2[threadIdx.x >> 6] = s2; }
    __syncthreads();
    if (threadIdx.x == 0) {
        float S  = w1[0] + w1[1] + w1[2] + w1[3];
        float S2 = w2[0] + w2[1] + w2[2] + w2[3];
        float n = (float)(B * N);
        float mean = S / n;
        float var = (S2 - S * S / n) / (n - 1.0f);
        var = fmaxf(var, 0.f);
        float inv = 1.0f / (sqrtf(var) + EPSN);
        stats[(which * C + c) * 2 + 0] = mean;
        stats[(which * C + c) * 2 + 1] = inv;
    }
}

// ---------------------------------------------------------------------------
// which 0: f (norm-folded, stats seg 0) / 1: g (seg 1) / 2: h (identity).
__global__ __launch_bounds__(256) void eff_weights_split(
    const float* __restrict__ Wf, const float* __restrict__ bf_,
    const float* __restrict__ Wg, const float* __restrict__ bg_,
    const float* __restrict__ Wh, const float* __restrict__ bh_,
    const float* __restrict__ stats,
    unsigned short* __restrict__ Wsf, unsigned short* __restrict__ Wsg,
    unsigned short* __restrict__ Wsh,
    float* __restrict__ bpf, float* __restrict__ bpg, float* __restrict__ bph)
{
    int o = blockIdx.x;
    int which = blockIdx.y;
    const float* W    = (which == 0) ? Wf  : (which == 1) ? Wg  : Wh;
    const float* bias = (which == 0) ? bf_ : (which == 1) ? bg_ : bh_;
    unsigned short* Ws = (which == 0) ? Wsf : (which == 1) ? Wsg : Wsh;
    float* bp          = (which == 0) ? bpf : (which == 1) ? bpg : bph;
    float corr = 0.f;
    for (int c = threadIdx.x; c < C; c += 256) {
        float wp;
        if (which < 2) {
            const float* st = stats + which * C * 2;
            wp = W[o * C + c] * st[c * 2 + 1];
            corr += wp * st[c * 2 + 0];
        } else {
            wp = W[o * C + c];
        }
        unsigned short h = f2bf(wp);
        unsigned short l = f2bf(wp - bf2f(h));
        Ws[(size_t)o * C2 + c]     = h;
        Ws[(size_t)o * C2 + C + c] = l;
    }
#pragma unroll
    for (int off = 32; off > 0; off >>= 1) corr += __shfl_down(corr, off);
    __shared__ float wr[4];
    if ((threadIdx.x & 63) == 0) wr[threadIdx.x >> 6] = corr;
    __syncthreads();
    if (threadIdx.x == 0) bp[o] = bias[o] - (wr[0] + wr[1] + wr[2] + wr[3]);
}

// ---------------------------------------------------------------------------
// Transpose + exact bf16 split for all three inputs of one batch in one launch:
// z selects source tensor and destination Xs buffer.
__global__ __launch_bounds__(256) void in_split_all(
    const float* __restrict__ F0, const float* __restrict__ F1,
    const float* __restrict__ F2,
    unsigned short* __restrict__ X0, unsigned short* __restrict__ X1,
    unsigned short* __restrict__ X2)
{
    int z = blockIdx.z;
    const float* F = (z == 0) ? F0 : (z == 1) ? F1 : F2;
    unsigned short* Xs = (z == 0) ? X0 : (z == 1) ? X1 : X2;
    __shared__ float t[64][65];
    int n0 = blockIdx.x * 64, c0 = blockIdx.y * 64;
    int tx = threadIdx.x & 15, ty = threadIdx.x >> 4;
#pragma unroll
    for (int it = 0; it < 4; ++it) {
        int cl = ty + it * 16;
        float4 v = *reinterpret_cast<const float4*>(&F[(size_t)(c0 + cl) * N + n0 + tx * 4]);
        t[cl][tx * 4 + 0] = v.x; t[cl][tx * 4 + 1] = v.y;
        t[cl][tx * 4 + 2] = v.z; t[cl][tx * 4 + 3] = v.w;
    }
    __syncthreads();
#pragma unroll
    for (int it = 0; it < 4; ++it) {
        int nl = ty + it * 16;
        unsigned short h[4], l[4];
#pragma unroll
        for (int j = 0; j < 4; ++j) {
            float v = t[tx * 4 + j][nl];
            h[j] = f2bf(v);
            l[j] = f2bf(v - bf2f(h[j]));
        }
        size_t base = (size_t)(n0 + nl) * C2 + c0 + tx * 4;
        *reinterpret_cast<ushort4*>(&Xs[base])     = make_ushort4(h[0], h[1], h[2], h[3]);
        *reinterpret_cast<ushort4*>(&Xs[base + C]) = make_ushort4(l[0], l[1], l[2], l[3]);
    }
}

// ---------------------------------------------------------------------------
// All three convs of one batch in one launch. z=0: Q (transposed-split out),
// z=1: K (same), z=2: V -> writes T = [bf16(V); qh; ql] directly.
// D[o,n] = sum_{k<1536} Astack[o,k]*Bstack[n,k] + bias[o];
// Astack = [Wh;Wl;Wh], Bstack = [Xh;Xh;Xl].
__global__ __launch_bounds__(256) void conv_all(
    const unsigned short* __restrict__ Wsf, const unsigned short* __restrict__ Wsg,
    const unsigned short* __restrict__ Wsh,
    const unsigned short* __restrict__ X0, const unsigned short* __restrict__ X1,
    const unsigned short* __restrict__ X2,
    const float* __restrict__ bpf, const float* __restrict__ bpg,
    const float* __restrict__ bph,
    unsigned short* __restrict__ Qs, unsigned short* __restrict__ Ks,
    unsigned short* __restrict__ Tb)
{
    int z = blockIdx.z;
    const unsigned short* Ws = (z == 0) ? Wsf : (z == 1) ? Wsg : Wsh;
    const unsigned short* Xs = (z == 0) ? X0  : (z == 1) ? X1  : X2;
    const float* bias        = (z == 0) ? bpf : (z == 1) ? bpg : bph;

    __shared__ unsigned short lA[128 * 32];
    __shared__ unsigned short lB[128 * 32];
    const int tid  = threadIdx.x;
    const int wave = tid >> 6, lane = tid & 63;
    const int o0 = blockIdx.y * 128;
    const int n0 = blockIdx.x * 128;
    const int wr = (wave >> 1) * 64, wc = (wave & 1) * 64;
    f32x4 acc[4][4] = {};
    const int r1 = tid >> 2, c1 = (tid & 3) * 8;
    const int r2 = r1 + 64;
    const int rowA = lane & 15;
    const int kk   = (lane >> 4) * 8;

    for (int k0 = 0; k0 < KS; k0 += 32) {
        int acol = (k0 < 1024) ? k0 : k0 - 1024;
        int bcol = (k0 < 512)  ? k0 : k0 - 512;
        __syncthreads();
        __builtin_amdgcn_global_load_lds(
            (const __attribute__((address_space(1))) void*)&Ws[(size_t)(o0 + r1) * C2 + acol + c1],
            (__attribute__((address_space(3))) void*)&lA[wave * 512], 16, 0, 0);
        __builtin_amdgcn_global_load_lds(
            (const __attribute__((address_space(1))) void*)&Ws[(size_t)(o0 + r2) * C2 + acol + c1],
            (__attribute__((address_space(3))) void*)&lA[2048 + wave * 512], 16, 0, 0);
        __builtin_amdgcn_global_load_lds(
            (const __attribute__((address_space(1))) void*)&Xs[(size_t)(n0 + r1) * C2 + bcol + c1],
            (__attribute__((address_space(3))) void*)&lB[wave * 512], 16, 0, 0);
        __builtin_amdgcn_global_load_lds(
            (const __attribute__((address_space(1))) void*)&Xs[(size_t)(n0 + r2) * C2 + bcol + c1],
            (__attribute__((address_space(3))) void*)&lB[2048 + wave * 512], 16, 0, 0);
        asm volatile("s_waitcnt vmcnt(0)" ::: "memory");
        __syncthreads();

        bf16x8 af[4], bfv[4];
#pragma unroll
        for (int f = 0; f < 4; ++f) {
            af[f]  = *reinterpret_cast<const bf16x8*>(&lA[(wr + f * 16 + rowA) * 32 + kk]);
            bfv[f] = *reinterpret_cast<const bf16x8*>(&lB[(wc + f * 16 + rowA) * 32 + kk]);
        }
#pragma unroll
        for (int fm = 0; fm < 4; ++fm)
#pragma unroll
            for (int fn = 0; fn < 4; ++fn)
                acc[fm][fn] = __builtin_amdgcn_mfma_f32_16x16x32_bf16(
                    af[fm], bfv[fn], acc[fm][fn], 0, 0, 0);
    }

    const int colD = lane & 15, rowD = (lane >> 4) * 4;
#pragma unroll
    for (int fm = 0; fm < 4; ++fm) {
        int ob = o0 + wr + fm * 16 + rowD;
        float4 b4 = *reinterpret_cast<const float4*>(&bias[ob]);
        float bv[4] = {b4.x, b4.y, b4.z, b4.w};
#pragma unroll
        for (int fn = 0; fn < 4; ++fn) {
            int n = n0 + wc + fn * 16 + colD;
            if (z < 2) {
                unsigned short* Yt = (z == 0) ? Qs : Ks;
                unsigned short hh[4], ll[4];
#pragma unroll
                for (int r = 0; r < 4; ++r) {
                    float val = acc[fm][fn][r] + bv[r];
                    hh[r] = f2bf(val);
                    ll[r] = f2bf(val - bf2f(hh[r]));
                }
                size_t base = (size_t)n * C2 + ob;
                *reinterpret_cast<ushort4*>(&Yt[base])     = make_ushort4(hh[0], hh[1], hh[2], hh[3]);
                *reinterpret_cast<ushort4*>(&Yt[base + C]) = make_ushort4(ll[0], ll[1], ll[2], ll[3]);
            } else {
#pragma unroll
                for (int r = 0; r < 4; ++r) {
                    float val = acc[fm][fn][r] + bv[r];
                    unsigned short vb = f2bf(val);
                    float vh = bf2f(vb);
                    float sq = vh * vh;                 // exact in fp32
                    unsigned short qb = f2bf(sq);
                    unsigned short lb = f2bf(sq - bf2f(qb));
                    size_t rowb = (size_t)(ob + r) * N + n;
                    Tb[rowb]                     = vb;
                    Tb[rowb + (size_t)C * N]     = qb;
                    Tb[rowb + (size_t)2 * C * N] = lb;
                }
            }
        }
    }
}

// ---------------------------------------------------------------------------
// Logits: L[nl,m] = sum_{k<1536} Qstack[nbase+nl,k] * Kstack[m,k]  (fp32 out).
__global__ __launch_bounds__(256) void gemm_qtk_mfma(
    const unsigned short* __restrict__ Qs,   // [N][2C]
    const unsigned short* __restrict__ Ks,   // [N][2C]
    float* __restrict__ L, int nbase)
{
    __shared__ unsigned short lA[128 * 32];
    __shared__ unsigned short lB[128 * 32];
    const int tid  = threadIdx.x;
    const int wave = tid >> 6, lane = tid & 63;
    const int nl0 = blockIdx.y * 128;
    const int qn0 = nbase + nl0;
    const int m0  = blockIdx.x * 128;
    const int wr = (wave >> 1) * 64, wc = (wave & 1) * 64;
    f32x4 acc[4][4] = {};
    const int r1 = tid >> 2, c1 = (tid & 3) * 8;
    const int r2 = r1 + 64;
    const int rowA = lane & 15;
    const int kk   = (lane >> 4) * 8;

    for (int k0 = 0; k0 < KS; k0 += 32) {
        int acol = (k0 < 1024) ? k0 : k0 - 1024;   // [Qh;Ql;Qh]
        int bcol = (k0 < 512)  ? k0 : k0 - 512;    // [Kh;Kh;Kl]
        __syncthreads();
        __builtin_amdgcn_global_load_lds(
            (const __attribute__((address_space(1))) void*)&Qs[(size_t)(qn0 + r1) * C2 + acol + c1],
            (__attribute__((address_space(3))) void*)&lA[wave * 512], 16, 0, 0);
        __builtin_amdgcn_global_load_lds(
            (const __attribute__((address_space(1))) void*)&Qs[(size_t)(qn0 + r2) * C2 + acol + c1],
            (__attribute__((address_space(3))) void*)&lA[2048 + wave * 512], 16, 0, 0);
        __builtin_amdgcn_global_load_lds(
            (const __attribute__((address_space(1))) void*)&Ks[(size_t)(m0 + r1) * C2 + bcol + c1],
            (__attribute__((address_space(3))) void*)&lB[wave * 512], 16, 0, 0);
        __builtin_amdgcn_global_load_lds(
            (const __attribute__((address_space(1))) void*)&Ks[(size_t)(m0 + r2) * C2 + bcol + c1],
            (__attribute__((address_space(3))) void*)&lB[2048 + wave * 512], 16, 0, 0);
        asm volatile("s_waitcnt vmcnt(0)" ::: "memory");
        __syncthreads();

        bf16x8 af[4], bfv[4];
#pragma unroll
        for (int f = 0; f < 4; ++f) {
            af[f]  = *reinterpret_cast<const bf16x8*>(&lA[(wr + f * 16 + rowA) * 32 + kk]);
            bfv[f] = *reinterpret_cast<const bf16x8*>(&lB[(wc + f * 16 + rowA) * 32 + kk]);
        }
#pragma unroll
        for (int fm = 0; fm < 4; ++fm)
#pragma unroll
            for (int fn = 0; fn < 4; ++fn)
                acc[fm][fn] = __builtin_amdgcn_mfma_f32_16x16x32_bf16(
                    af[fm], bfv[fn], acc[fm][fn], 0, 0, 0);
    }

    const int colD = lane & 15, rowD = (lane >> 4) * 4;
#pragma unroll
    for (int fm = 0; fm < 4; ++fm)
#pragma unroll
        for (int fn = 0; fn < 4; ++fn) {
            int col = m0 + wc + fn * 16 + colD;
            int row = nl0 + wr + fm * 16 + rowD;
#pragma unroll
            for (int r = 0; r < 4; ++r)
                L[(size_t)(row + r) * N + col] = acc[fm][fn][r];
        }
}

// ---------------------------------------------------------------------------
// Row softmax -> unnormalized bf16 weights + exact fp32 row-sum inverse.
__global__ __launch_bounds__(256) void softmax_bf16(
    const float* __restrict__ L, unsigned short* __restrict__ E,
    float* __restrict__ rowinv)
{
    __shared__ float row[N];
    __shared__ float red[4];
    const float* Lr = L + (size_t)blockIdx.x * N;
    unsigned short* Er = E + (size_t)blockIdx.x * N;
    float mx = -3.0e38f;
    for (int i = threadIdx.x; i < N / 4; i += 256) {
        float4 v = reinterpret_cast<const float4*>(Lr)[i];
        reinterpret_cast<float4*>(row)[i] = v;
        mx = fmaxf(fmaxf(mx, fmaxf(v.x, v.y)), fmaxf(v.z, v.w));
    }
#pragma unroll
    for (int off = 32; off > 0; off >>= 1) mx = fmaxf(mx, __shfl_xor(mx, off));
    if ((threadIdx.x & 63) == 0) red[threadIdx.x >> 6] = mx;
    __syncthreads();
    mx = fmaxf(fmaxf(red[0], red[1]), fmaxf(red[2], red[3]));
    __syncthreads();
    float s = 0.f;
    for (int i = threadIdx.x; i < N / 4; i += 256) {
        float4 v = reinterpret_cast<float4*>(row)[i];
        unsigned short e0 = f2bf(__expf(v.x - mx));
        unsigned short e1 = f2bf(__expf(v.y - mx));
        unsigned short e2 = f2bf(__expf(v.z - mx));
        unsigned short e3 = f2bf(__expf(v.w - mx));
        s += bf2f(e0) + bf2f(e1) + bf2f(e2) + bf2f(e3);
        reinterpret_cast<ushort4*>(Er)[i] = make_ushort4(e0, e1, e2, e3);
    }
#pragma unroll
    for (int off = 32; off > 0; off >>= 1) s += __shfl_xor(s, off);
    if ((threadIdx.x & 63) == 0) red[threadIdx.x >> 6] = s;
    __syncthreads();
    if (threadIdx.x == 0)
        rowinv[blockIdx.x] = 1.0f / (red[0] + red[1] + red[2] + red[3]);
}

// ---------------------------------------------------------------------------
// Split-K moments: Ppart[kz][v,n] = sum_{m in half kz} T[v,m] * E[n,m].
__global__ __launch_bounds__(256) void gemm_av_splitk(
    const unsigned short* __restrict__ T,   // [3C][N]
    const unsigned short* __restrict__ E,   // [NC][N]
    float* __restrict__ P)                  // [2][3C][NC]
{
    __shared__ unsigned short lA[128 * 32];
    __shared__ unsigned short lB[128 * 32];
    const int tid  = threadIdx.x;
    const int wave = tid >> 6, lane = tid & 63;
    const int v0 = blockIdx.y * 128;
    const int n0 = blockIdx.x * 128;
    const int kz = blockIdx.z;
    const int kbeg = kz * HK;
    const int wr = (wave >> 1) * 64, wc = (wave & 1) * 64;
    f32x4 acc[4][4] = {};
    const int r1 = tid >> 2, c1 = (tid & 3) * 8;
    const int r2 = r1 + 64;
    const int rowA = lane & 15;
    const int kk   = (lane >> 4) * 8;

    for (int k0 = kbeg; k0 < kbeg + HK; k0 += 32) {
        __syncthreads();
        __builtin_amdgcn_global_load_lds(
            (const __attribute__((address_space(1))) void*)&T[(size_t)(v0 + r1) * N + k0 + c1],
            (__attribute__((address_space(3))) void*)&lA[wave * 512], 16, 0, 0);
        __builtin_amdgcn_global_load_lds(
            (const __attribute__((address_space(1))) void*)&T[(size_t)(v0 + r2) * N + k0 + c1],
            (__attribute__((address_space(3))) void*)&lA[2048 + wave * 512], 16, 0, 0);
        __builtin_amdgcn_global_load_lds(
            (const __attribute__((address_space(1))) void*)&E[(size_t)(n0 + r1) * N + k0 + c1],
            (__attribute__((address_space(3))) void*)&lB[wave * 512], 16, 0, 0);
        __builtin_amdgcn_global_load_lds(
            (const __attribute__((address_space(1))) void*)&E[(size_t)(n0 + r2) * N + k0 + c1],
            (__attribute__((address_space(3))) void*)&lB[2048 + wave * 512], 16, 0, 0);
        asm volatile("s_waitcnt vmcnt(0)" ::: "memory");
        __syncthreads();

        bf16x8 af[4], bfv[4];
#pragma unroll
        for (int f = 0; f < 4; ++f) {
            af[f]  = *reinterpret_cast<const bf16x8*>(&lA[(wr + f * 16 + rowA) * 32 + kk]);
            bfv[f] = *reinterpret_cast<const bf16x8*>(&lB[(wc + f * 16 + rowA) * 32 + kk]);
        }
#pragma unroll
        for (int fm = 0; fm < 4; ++fm)
#pragma unroll
            for (int fn = 0; fn < 4; ++fn)
                acc[fm][fn] = __builtin_amdgcn_mfma_f32_16x16x32_bf16(
                    af[fm], bfv[fn], acc[fm][fn], 0, 0, 0);
    }

    float* Pz = P + (size_t)kz * 3 * C * NC;
    const int colD = lane & 15, rowD = (lane >> 4) * 4;
#pragma unroll
    for (int fm = 0; fm < 4; ++fm)
#pragma unroll
        for (int fn = 0; fn < 4; ++fn) {
            int col = n0 + wc + fn * 16 + colD;
            int row = v0 + wr + fm * 16 + rowD;
#pragma unroll
            for (int r = 0; r < 4; ++r)
                Pz[(size_t)(row + r) * NC + col] = acc[fm][fn][r];
        }
}

// ---------------------------------------------------------------------------
// Combine split-K partials + moment epilogue.
__global__ __launch_bounds__(256) void av_epilogue2(
    const float* __restrict__ P, const float* __restrict__ rowinv,
    const float* __restrict__ Fc, const float* __restrict__ st3,
    float* __restrict__ out, int nbase)
{
    const size_t PS = (size_t)3 * C * NC;
    int idx = blockIdx.x * 256 + threadIdx.x;      // over C*NC/4
    int v = idx >> 9;
    int n = (idx & 511) * 4;
    float4 pm0 = *reinterpret_cast<const float4*>(&P[(size_t)v * NC + n]);
    float4 ph0 = *reinterpret_cast<const float4*>(&P[(size_t)(C + v) * NC + n]);
    float4 pl0 = *reinterpret_cast<const float4*>(&P[(size_t)(2 * C + v) * NC + n]);
    float4 pm1 = *reinterpret_cast<const float4*>(&P[PS + (size_t)v * NC + n]);
    float4 ph1 = *reinterpret_cast<const float4*>(&P[PS + (size_t)(C + v) * NC + n]);
    float4 pl1 = *reinterpret_cast<const float4*>(&P[PS + (size_t)(2 * C + v) * NC + n]);
    float4 ri = *reinterpret_cast<const float4*>(&rowinv[n]);
    float mean = st3[v * 2], inv = st3[v * 2 + 1];
    float4 fc = *reinterpret_cast<const float4*>(&Fc[(size_t)v * N + nbase + n]);
    float pmv[4] = {pm0.x + pm1.x, pm0.y + pm1.y, pm0.z + pm1.z, pm0.w + pm1.w};
    float phv[4] = {ph0.x + ph1.x + pl0.x + pl1.x, ph0.y + ph1.y + pl0.y + pl1.y,
                    ph0.z + ph1.z + pl0.z + pl1.z, ph0.w + ph1.w + pl0.w + pl1.w};
    float riv[4] = {ri.x, ri.y, ri.z, ri.w};
    float fcv[4] = {fc.x, fc.y, fc.z, fc.w};
    float o[4];
#pragma unroll
    for (int q = 0; q < 4; ++q) {
        float M  = pmv[q] * riv[q];
        float S2 = phv[q] * riv[q];
        float var = fmaxf(S2 - M * M, 0.f) + EPSV;
        o[q] = sqrtf(var) * ((fcv[q] - mean) * inv) + M;
    }
    *reinterpret_cast<float4*>(&out[(size_t)v * N + nbase + n]) =
        make_float4(o[0], o[1], o[2], o[3]);
}

// ---------------------------------------------------------------------------
extern "C" void kernel_launch(void* const* d_in, const int* in_sizes, int n_in,
                              void* d_out, int out_size, void* d_ws, size_t ws_size,
                              hipStream_t stream)
{
    const float* F_c      = (const float*)d_in[0];
    const float* F_s      = (const float*)d_in[1];
    const float* F_c_prev = (const float*)d_in[2];
    const float* F_s_prev = (const float*)d_in[3];
    const float* Wf = (const float*)d_in[4];
    const float* bf_ = (const float*)d_in[5];
    const float* Wg = (const float*)d_in[6];
    const float* bg_ = (const float*)d_in[7];
    const float* Wh = (const float*)d_in[8];
    const float* bh_ = (const float*)d_in[9];
    float* out = (float*)d_out;

    // byte-offset workspace carve-up, 256B aligned regions
    char* base = (char*)d_ws;
    size_t off = 0;
    auto alloc = [&](size_t bytes) { void* p = base + off; off = (off + bytes + 255) & ~(size_t)255; return p; };
    float* stats = (float*)alloc(3 * C * 2 * 4);
    float* bpf   = (float*)alloc(C * 4);
    float* bpg   = (float*)alloc(C * 4);
    float* bph   = (float*)alloc(C * 4);
    float* rinv  = (float*)alloc(NC * 4);
    unsigned short* Wsf = (unsigned short*)alloc((size_t)C * C2 * 2);   // 1 MB
    unsigned short* Wsg = (unsigned short*)alloc((size_t)C * C2 * 2);
    unsigned short* Wsh = (unsigned short*)alloc((size_t)C * C2 * 2);
    unsigned short* Qs  = (unsigned short*)alloc((size_t)N * C2 * 2);   // 8 MB
    unsigned short* Ks  = (unsigned short*)alloc((size_t)N * C2 * 2);   // 8 MB
    unsigned short* Tb  = (unsigned short*)alloc((size_t)3 * C * N * 2);// 12.6 MB
    // L region (33.5 MB): conv-phase hosts Xs0/Xs1/Xs2 (24 MB); attention phase
    // hosts L, then split-K P partials (25.2 MB) after softmax consumed L.
    char* Lreg = (char*)alloc((size_t)NC * N * 4);
    float* Lb = (float*)Lreg;
    float* Pb = (float*)Lreg;
    unsigned short* Xs0 = (unsigned short*)Lreg;
    unsigned short* Xs1 = (unsigned short*)(Lreg + (size_t)N * C2 * 2);
    unsigned short* Xs2 = (unsigned short*)(Lreg + (size_t)2 * N * C2 * 2);
    unsigned short* Eb  = (unsigned short*)alloc((size_t)NC * N * 2);   // 16.8 MB
    if (ws_size < off) return;  // insufficient scratch -> visible failure

    hipLaunchKernelGGL(stats_kernel, dim3(C, 3), dim3(256), 0, stream,
                       F_c_prev, F_s_prev, F_c, stats);
    hipLaunchKernelGGL(eff_weights_split, dim3(C, 3), dim3(256), 0, stream,
                       Wf, bf_, Wg, bg_, Wh, bh_, stats, Wsf, Wsg, Wsh, bpf, bpg, bph);

    for (int b = 0; b < B; ++b) {
        const float* Xq = F_c_prev + (size_t)b * C * N;
        const float* Xk = F_s_prev + (size_t)b * C * N;
        const float* Xv = F_s      + (size_t)b * C * N;

        hipLaunchKernelGGL(in_split_all, dim3(N / 64, C / 64, 3), dim3(256), 0, stream,
                           Xq, Xk, Xv, Xs0, Xs1, Xs2);
        hipLaunchKernelGGL(conv_all, dim3(N / 128, C / 128, 3), dim3(256), 0, stream,
                           Wsf, Wsg, Wsh, Xs0, Xs1, Xs2, bpf, bpg, bph, Qs, Ks, Tb);

        for (int chunk = 0; chunk < N / NC; ++chunk) {
            int nbase = chunk * NC;
            hipLaunchKernelGGL(gemm_qtk_mfma, dim3(N / 128, NC / 128), dim3(256), 0, stream,
                               Qs, Ks, Lb, nbase);
            hipLaunchKernelGGL(softmax_bf16, dim3(NC), dim3(256), 0, stream, Lb, Eb, rinv);
            hipLaunchKernelGGL(gemm_av_splitk, dim3(NC / 128, 3 * C / 128, 2), dim3(256), 0, stream,
                               Tb, Eb, Pb);
            hipLaunchKernelGGL(av_epilogue2, dim3((C * NC / 4) / 256), dim3(256), 0, stream,
                               Pb, rinv, F_c + (size_t)b * C * N, stats + 2 * C * 2,
                               out + (size_t)b * C * N, nbase);
        }
    }
}

// Round 5
// 1177.124 us; speedup vs baseline: 4.2125x; 1.0282x over previous
//
#include <hip/hip_runtime.h>
#include <math.h>

// AdaAttN — all GEMMs on bf16 MFMA. Round 5: occupancy round.
// 128x64 tiles everywhere (grids 768-1024 blocks, 3-4 blocks/CU), merged-chunk
// AV GEMM (E straddles two workspace regions), XCD-aware block swizzle.

constexpr int B = 4;
constexpr int C = 512;     // Cqk == Cv == 512
constexpr int N = 4096;    // H*W
constexpr int NC = 2048;   // n-chunk for logits/softmax
constexpr int C2 = 2 * C;  // split row length
constexpr int KS = 3 * C;  // split-GEMM depth (convs & logits)
constexpr float EPSN = 1e-12f;
constexpr float EPSV = 1e-8f;

typedef __attribute__((ext_vector_type(4))) float f32x4;
typedef __attribute__((ext_vector_type(8))) short bf16x8;

static __device__ __forceinline__ unsigned short f2bf(float x) {
    union { float f; unsigned u; } c; c.f = x;
    unsigned r = c.u + 0x7FFFu + ((c.u >> 16) & 1u);   // RNE (finite inputs)
    return (unsigned short)(r >> 16);
}
static __device__ __forceinline__ float bf2f(unsigned short b) {
    union { unsigned u; float f; } c; c.u = ((unsigned)b) << 16;
    return c.f;
}

// XCD-aware swizzle: GX fixed at 64; nwg = 64*gy, always %8==0 -> bijective.
static __device__ __forceinline__ void xcd_swz(int gy, int& bx, int& by) {
    int nwg = gy << 6;
    int oldid = blockIdx.y * 64 + blockIdx.x;
    int nid = (oldid & 7) * (nwg >> 3) + (oldid >> 3);
    bx = nid & 63;
    by = nid >> 6;
}

// ---------------------------------------------------------------------------
__global__ __launch_bounds__(256) void stats_kernel(
    const float* __restrict__ fcp, const float* __restrict__ fsp,
    const float* __restrict__ fc, float* __restrict__ stats)
{
    int c = blockIdx.x;
    int which = blockIdx.y;
    const float* src = (which == 0) ? fcp : ((which == 1) ? fsp : fc);
    float s = 0.f, s2 = 0.f;
    for (int b = 0; b < B; ++b) {
        const float4* p = reinterpret_cast<const float4*>(src + (size_t)(b * C + c) * N);
        for (int i = threadIdx.x; i < N / 4; i += 256) {
            float4 v = p[i];
            s  += v.x + v.y + v.z + v.w;
            s2 += v.x * v.x + v.y * v.y + v.z * v.z + v.w * v.w;
        }
    }
#pragma unroll
    for (int off = 32; off > 0; off >>= 1) {
        s  += __shfl_down(s, off);
        s2 += __shfl_down(s2, off);
    }
    __shared__ float w1[4], w2[4];
    if ((threadIdx.x & 63) == 0) { w1[threadIdx.x >> 6] = s; w2[threadIdx.x >> 6] = s2; }
    __syncthreads();
    if (threadIdx.x == 0) {
        float S  = w1[0] + w1[1] + w1[2] + w1[3];
        float S2 = w2[0] + w2[1] + w2[2] + w2[3];
        float n = (float)(B * N);
        float mean = S / n;
        float var = (S2 - S * S / n) / (n - 1.0f);
        var = fmaxf(var, 0.f);
        float inv = 1.0f / (sqrtf(var) + EPSN);
        stats[(which * C + c) * 2 + 0] = mean;
        stats[(which * C + c) * 2 + 1] = inv;
    }
}

// ---------------------------------------------------------------------------
__global__ __launch_bounds__(256) void eff_weights_split(
    const float* __restrict__ Wf, const float* __restrict__ bf_,
    const float* __restrict__ Wg, const float* __restrict__ bg_,
    const float* __restrict__ Wh, const float* __restrict__ bh_,
    const float* __restrict__ stats,
    unsigned short* __restrict__ Wsf, unsigned short* __restrict__ Wsg,
    unsigned short* __restrict__ Wsh,
    float* __restrict__ bpf, float* __restrict__ bpg, float* __restrict__ bph)
{
    int o = blockIdx.x;
    int which = blockIdx.y;
    const float* W    = (which == 0) ? Wf  : (which == 1) ? Wg  : Wh;
    const float* bias = (which == 0) ? bf_ : (which == 1) ? bg_ : bh_;
    unsigned short* Ws = (which == 0) ? Wsf : (which == 1) ? Wsg : Wsh;
    float* bp          = (which == 0) ? bpf : (which == 1) ? bpg : bph;
    float corr = 0.f;
    for (int c = threadIdx.x; c < C; c += 256) {
        float wp;
        if (which < 2) {
            const float* st = stats + which * C * 2;
            wp = W[o * C + c] * st[c * 2 + 1];
            corr += wp * st[c * 2 + 0];
        } else {
            wp = W[o * C + c];
        }
        unsigned short h = f2bf(wp);
        unsigned short l = f2bf(wp - bf2f(h));
        Ws[(size_t)o * C2 + c]     = h;
        Ws[(size_t)o * C2 + C + c] = l;
    }
#pragma unroll
    for (int off = 32; off > 0; off >>= 1) corr += __shfl_down(corr, off);
    __shared__ float wr[4];
    if ((threadIdx.x & 63) == 0) wr[threadIdx.x >> 6] = corr;
    __syncthreads();
    if (threadIdx.x == 0) bp[o] = bias[o] - (wr[0] + wr[1] + wr[2] + wr[3]);
}

// ---------------------------------------------------------------------------
// Transpose + exact bf16 split: F [C][N] f32 -> Xs [N][2C] bf16 (h | l). z = which input.
__global__ __launch_bounds__(256) void in_split_all(
    const float* __restrict__ F0, const float* __restrict__ F1,
    const float* __restrict__ F2,
    unsigned short* __restrict__ X0, unsigned short* __restrict__ X1,
    unsigned short* __restrict__ X2)
{
    int z = blockIdx.z;
    const float* F = (z == 0) ? F0 : (z == 1) ? F1 : F2;
    unsigned short* Xs = (z == 0) ? X0 : (z == 1) ? X1 : X2;
    __shared__ float t[64][65];
    int n0 = blockIdx.x * 64, c0 = blockIdx.y * 64;
    int tx = threadIdx.x & 15, ty = threadIdx.x >> 4;
#pragma unroll
    for (int it = 0; it < 4; ++it) {
        int cl = ty + it * 16;
        float4 v = *reinterpret_cast<const float4*>(&F[(size_t)(c0 + cl) * N + n0 + tx * 4]);
        t[cl][tx * 4 + 0] = v.x; t[cl][tx * 4 + 1] = v.y;
        t[cl][tx * 4 + 2] = v.z; t[cl][tx * 4 + 3] = v.w;
    }
    __syncthreads();
#pragma unroll
    for (int it = 0; it < 4; ++it) {
        int nl = ty + it * 16;
        unsigned short h[4], l[4];
#pragma unroll
        for (int j = 0; j < 4; ++j) {
            float v = t[tx * 4 + j][nl];
            h[j] = f2bf(v);
            l[j] = f2bf(v - bf2f(h[j]));
        }
        size_t base = (size_t)(n0 + nl) * C2 + c0 + tx * 4;
        *reinterpret_cast<ushort4*>(&Xs[base])     = make_ushort4(h[0], h[1], h[2], h[3]);
        *reinterpret_cast<ushort4*>(&Xs[base + C]) = make_ushort4(l[0], l[1], l[2], l[3]);
    }
}

// ---------------------------------------------------------------------------
// 3-way conv, tile 128(o) x 64(n), K=1536 stacked. z=0:Q z=1:K (transposed split
// out), z=2: V -> T rows [bf16(V); qh; ql].
__global__ __launch_bounds__(256) void conv_all(
    const unsigned short* __restrict__ Wsf, const unsigned short* __restrict__ Wsg,
    const unsigned short* __restrict__ Wsh,
    const unsigned short* __restrict__ X0, const unsigned short* __restrict__ X1,
    const unsigned short* __restrict__ X2,
    const float* __restrict__ bpf, const float* __restrict__ bpg,
    const float* __restrict__ bph,
    unsigned short* __restrict__ Qs, unsigned short* __restrict__ Ks,
    unsigned short* __restrict__ Tb)
{
    int z = blockIdx.z;
    const unsigned short* Ws = (z == 0) ? Wsf : (z == 1) ? Wsg : Wsh;
    const unsigned short* Xs = (z == 0) ? X0  : (z == 1) ? X1  : X2;
    const float* bias        = (z == 0) ? bpf : (z == 1) ? bpg : bph;

    __shared__ unsigned short lA[128 * 32];
    __shared__ unsigned short lB[64 * 32];
    const int tid  = threadIdx.x;
    const int wave = tid >> 6, lane = tid & 63;
    int bx, by; xcd_swz(4, bx, by);
    const int o0 = by * 128;
    const int n0 = bx * 64;
    const int wr = (wave >> 1) * 64, wc = (wave & 1) * 32;
    f32x4 acc[4][2] = {};
    const int r1 = tid >> 2, c1 = (tid & 3) * 8;
    const int r2 = r1 + 64;
    const int rowA = lane & 15;
    const int kk   = (lane >> 4) * 8;

    for (int k0 = 0; k0 < KS; k0 += 32) {
        int acol = (k0 < 1024) ? k0 : k0 - 1024;
        int bcol = (k0 < 512)  ? k0 : k0 - 512;
        __syncthreads();
        __builtin_amdgcn_global_load_lds(
            (const __attribute__((address_space(1))) void*)&Ws[(size_t)(o0 + r1) * C2 + acol + c1],
            (__attribute__((address_space(3))) void*)&lA[wave * 512], 16, 0, 0);
        __builtin_amdgcn_global_load_lds(
            (const __attribute__((address_space(1))) void*)&Ws[(size_t)(o0 + r2) * C2 + acol + c1],
            (__attribute__((address_space(3))) void*)&lA[2048 + wave * 512], 16, 0, 0);
        __builtin_amdgcn_global_load_lds(
            (const __attribute__((address_space(1))) void*)&Xs[(size_t)(n0 + r1) * C2 + bcol + c1],
            (__attribute__((address_space(3))) void*)&lB[wave * 512], 16, 0, 0);
        asm volatile("s_waitcnt vmcnt(0)" ::: "memory");
        __syncthreads();

        bf16x8 af[4], bfv[2];
#pragma unroll
        for (int f = 0; f < 4; ++f)
            af[f]  = *reinterpret_cast<const bf16x8*>(&lA[(wr + f * 16 + rowA) * 32 + kk]);
#pragma unroll
        for (int f = 0; f < 2; ++f)
            bfv[f] = *reinterpret_cast<const bf16x8*>(&lB[(wc + f * 16 + rowA) * 32 + kk]);
#pragma unroll
        for (int fm = 0; fm < 4; ++fm)
#pragma unroll
            for (int fn = 0; fn < 2; ++fn)
                acc[fm][fn] = __builtin_amdgcn_mfma_f32_16x16x32_bf16(
                    af[fm], bfv[fn], acc[fm][fn], 0, 0, 0);
    }

    const int colD = lane & 15, rowD = (lane >> 4) * 4;
#pragma unroll
    for (int fm = 0; fm < 4; ++fm) {
        int ob = o0 + wr + fm * 16 + rowD;
        float4 b4 = *reinterpret_cast<const float4*>(&bias[ob]);
        float bv[4] = {b4.x, b4.y, b4.z, b4.w};
#pragma unroll
        for (int fn = 0; fn < 2; ++fn) {
            int n = n0 + wc + fn * 16 + colD;
            if (z < 2) {
                unsigned short* Yt = (z == 0) ? Qs : Ks;
                unsigned short hh[4], ll[4];
#pragma unroll
                for (int r = 0; r < 4; ++r) {
                    float val = acc[fm][fn][r] + bv[r];
                    hh[r] = f2bf(val);
                    ll[r] = f2bf(val - bf2f(hh[r]));
                }
                size_t base = (size_t)n * C2 + ob;
                *reinterpret_cast<ushort4*>(&Yt[base])     = make_ushort4(hh[0], hh[1], hh[2], hh[3]);
                *reinterpret_cast<ushort4*>(&Yt[base + C]) = make_ushort4(ll[0], ll[1], ll[2], ll[3]);
            } else {
#pragma unroll
                for (int r = 0; r < 4; ++r) {
                    float val = acc[fm][fn][r] + bv[r];
                    unsigned short vb = f2bf(val);
                    float vh = bf2f(vb);
                    float sq = vh * vh;                 // exact in fp32
                    unsigned short qb = f2bf(sq);
                    unsigned short lb = f2bf(sq - bf2f(qb));
                    size_t rowb = (size_t)(ob + r) * N + n;
                    Tb[rowb]                     = vb;
                    Tb[rowb + (size_t)C * N]     = qb;
                    Tb[rowb + (size_t)2 * C * N] = lb;
                }
            }
        }
    }
}

// ---------------------------------------------------------------------------
// Logits: L[nl,m] = sum_{k<1536} Qstack[nbase+nl,k]*Kstack[m,k]. Tile 128(n)x64(m).
__global__ __launch_bounds__(256) void gemm_qtk_mfma(
    const unsigned short* __restrict__ Qs,   // [N][2C]
    const unsigned short* __restrict__ Ks,   // [N][2C]
    float* __restrict__ L, int nbase)
{
    __shared__ unsigned short lA[128 * 32];
    __shared__ unsigned short lB[64 * 32];
    const int tid  = threadIdx.x;
    const int wave = tid >> 6, lane = tid & 63;
    int bx, by; xcd_swz(16, bx, by);
    const int nl0 = by * 128;
    const int qn0 = nbase + nl0;
    const int m0  = bx * 64;
    const int wr = (wave >> 1) * 64, wc = (wave & 1) * 32;
    f32x4 acc[4][2] = {};
    const int r1 = tid >> 2, c1 = (tid & 3) * 8;
    const int r2 = r1 + 64;
    const int rowA = lane & 15;
    const int kk   = (lane >> 4) * 8;

    for (int k0 = 0; k0 < KS; k0 += 32) {
        int acol = (k0 < 1024) ? k0 : k0 - 1024;   // [Qh;Ql;Qh]
        int bcol = (k0 < 512)  ? k0 : k0 - 512;    // [Kh;Kh;Kl]
        __syncthreads();
        __builtin_amdgcn_global_load_lds(
            (const __attribute__((address_space(1))) void*)&Qs[(size_t)(qn0 + r1) * C2 + acol + c1],
            (__attribute__((address_space(3))) void*)&lA[wave * 512], 16, 0, 0);
        __builtin_amdgcn_global_load_lds(
            (const __attribute__((address_space(1))) void*)&Qs[(size_t)(qn0 + r2) * C2 + acol + c1],
            (__attribute__((address_space(3))) void*)&lA[2048 + wave * 512], 16, 0, 0);
        __builtin_amdgcn_global_load_lds(
            (const __attribute__((address_space(1))) void*)&Ks[(size_t)(m0 + r1) * C2 + bcol + c1],
            (__attribute__((address_space(3))) void*)&lB[wave * 512], 16, 0, 0);
        asm volatile("s_waitcnt vmcnt(0)" ::: "memory");
        __syncthreads();

        bf16x8 af[4], bfv[2];
#pragma unroll
        for (int f = 0; f < 4; ++f)
            af[f]  = *reinterpret_cast<const bf16x8*>(&lA[(wr + f * 16 + rowA) * 32 + kk]);
#pragma unroll
        for (int f = 0; f < 2; ++f)
            bfv[f] = *reinterpret_cast<const bf16x8*>(&lB[(wc + f * 16 + rowA) * 32 + kk]);
#pragma unroll
        for (int fm = 0; fm < 4; ++fm)
#pragma unroll
            for (int fn = 0; fn < 2; ++fn)
                acc[fm][fn] = __builtin_amdgcn_mfma_f32_16x16x32_bf16(
                    af[fm], bfv[fn], acc[fm][fn], 0, 0, 0);
    }

    const int colD = lane & 15, rowD = (lane >> 4) * 4;
#pragma unroll
    for (int fm = 0; fm < 4; ++fm)
#pragma unroll
        for (int fn = 0; fn < 2; ++fn) {
            int col = m0 + wc + fn * 16 + colD;
            int row = nl0 + wr + fm * 16 + rowD;
#pragma unroll
            for (int r = 0; r < 4; ++r)
                L[(size_t)(row + r) * N + col] = acc[fm][fn][r];
        }
}

// ---------------------------------------------------------------------------
// Row softmax -> unnormalized bf16 weights (into chunk's E region) + fp32 1/rowsum.
__global__ __launch_bounds__(256) void softmax_bf16(
    const float* __restrict__ L, unsigned short* __restrict__ E,
    float* __restrict__ rinv, int nbase)
{
    __shared__ float row[N];
    __shared__ float red[4];
    const float* Lr = L + (size_t)blockIdx.x * N;
    unsigned short* Er = E + (size_t)blockIdx.x * N;
    float mx = -3.0e38f;
    for (int i = threadIdx.x; i < N / 4; i += 256) {
        float4 v = reinterpret_cast<const float4*>(Lr)[i];
        reinterpret_cast<float4*>(row)[i] = v;
        mx = fmaxf(fmaxf(mx, fmaxf(v.x, v.y)), fmaxf(v.z, v.w));
    }
#pragma unroll
    for (int off = 32; off > 0; off >>= 1) mx = fmaxf(mx, __shfl_xor(mx, off));
    if ((threadIdx.x & 63) == 0) red[threadIdx.x >> 6] = mx;
    __syncthreads();
    mx = fmaxf(fmaxf(red[0], red[1]), fmaxf(red[2], red[3]));
    __syncthreads();
    float s = 0.f;
    for (int i = threadIdx.x; i < N / 4; i += 256) {
        float4 v = reinterpret_cast<float4*>(row)[i];
        unsigned short e0 = f2bf(__expf(v.x - mx));
        unsigned short e1 = f2bf(__expf(v.y - mx));
        unsigned short e2 = f2bf(__expf(v.z - mx));
        unsigned short e3 = f2bf(__expf(v.w - mx));
        s += bf2f(e0) + bf2f(e1) + bf2f(e2) + bf2f(e3);
        reinterpret_cast<ushort4*>(Er)[i] = make_ushort4(e0, e1, e2, e3);
    }
#pragma unroll
    for (int off = 32; off > 0; off >>= 1) s += __shfl_xor(s, off);
    if ((threadIdx.x & 63) == 0) red[threadIdx.x >> 6] = s;
    __syncthreads();
    if (threadIdx.x == 0)
        rinv[nbase + blockIdx.x] = 1.0f / (red[0] + red[1] + red[2] + red[3]);
}

// ---------------------------------------------------------------------------
// Moments: P[v,n] = sum_m T[v,m] * E[n,m], full n (E in two half-regions).
// Tile 128(v) x 64(n), K=4096.
__global__ __launch_bounds__(256) void gemm_av_mfma(
    const unsigned short* __restrict__ T,    // [3C][N]
    const unsigned short* __restrict__ E0,   // rows [0,2048)
    const unsigned short* __restrict__ E1,   // rows [2048,4096)
    float* __restrict__ P)                   // [3C][N]
{
    __shared__ unsigned short lA[128 * 32];
    __shared__ unsigned short lB[64 * 32];
    const int tid  = threadIdx.x;
    const int wave = tid >> 6, lane = tid & 63;
    int bx, by; xcd_swz(12, bx, by);
    const int v0 = by * 128;
    const int n0 = bx * 64;
    const unsigned short* Ep = (n0 < NC) ? E0 + (size_t)n0 * N
                                         : E1 + (size_t)(n0 - NC) * N;
    const int wr = (wave >> 1) * 64, wc = (wave & 1) * 32;
    f32x4 acc[4][2] = {};
    const int r1 = tid >> 2, c1 = (tid & 3) * 8;
    const int r2 = r1 + 64;
    const int rowA = lane & 15;
    const int kk   = (lane >> 4) * 8;

    for (int k0 = 0; k0 < N; k0 += 32) {
        __syncthreads();
        __builtin_amdgcn_global_load_lds(
            (const __attribute__((address_space(1))) void*)&T[(size_t)(v0 + r1) * N + k0 + c1],
            (__attribute__((address_space(3))) void*)&lA[wave * 512], 16, 0, 0);
        __builtin_amdgcn_global_load_lds(
            (const __attribute__((address_space(1))) void*)&T[(size_t)(v0 + r2) * N + k0 + c1],
            (__attribute__((address_space(3))) void*)&lA[2048 + wave * 512], 16, 0, 0);
        __builtin_amdgcn_global_load_lds(
            (const __attribute__((address_space(1))) void*)&Ep[(size_t)r1 * N + k0 + c1],
            (__attribute__((address_space(3))) void*)&lB[wave * 512], 16, 0, 0);
        asm volatile("s_waitcnt vmcnt(0)" ::: "memory");
        __syncthreads();

        bf16x8 af[4], bfv[2];
#pragma unroll
        for (int f = 0; f < 4; ++f)
            af[f]  = *reinterpret_cast<const bf16x8*>(&lA[(wr + f * 16 + rowA) * 32 + kk]);
#pragma unroll
        for (int f = 0; f < 2; ++f)
            bfv[f] = *reinterpret_cast<const bf16x8*>(&lB[(wc + f * 16 + rowA) * 32 + kk]);
#pragma unroll
        for (int fm = 0; fm < 4; ++fm)
#pragma unroll
            for (int fn = 0; fn < 2; ++fn)
                acc[fm][fn] = __builtin_amdgcn_mfma_f32_16x16x32_bf16(
                    af[fm], bfv[fn], acc[fm][fn], 0, 0, 0);
    }

    const int colD = lane & 15, rowD = (lane >> 4) * 4;
#pragma unroll
    for (int fm = 0; fm < 4; ++fm)
#pragma unroll
        for (int fn = 0; fn < 2; ++fn) {
            int col = n0 + wc + fn * 16 + colD;
            int row = v0 + wr + fm * 16 + rowD;
#pragma unroll
            for (int r = 0; r < 4; ++r)
                P[(size_t)(row + r) * N + col] = acc[fm][fn][r];
        }
}

// ---------------------------------------------------------------------------
// Full-N moment epilogue.
__global__ __launch_bounds__(256) void av_epilogue(
    const float* __restrict__ P, const float* __restrict__ rinv,
    const float* __restrict__ Fc, const float* __restrict__ st3,
    float* __restrict__ out)
{
    int idx = blockIdx.x * 256 + threadIdx.x;      // over C*N/4
    int v = idx >> 10;                             // / (N/4)
    int n = (idx & 1023) * 4;
    float4 pm = *reinterpret_cast<const float4*>(&P[(size_t)v * N + n]);
    float4 ph = *reinterpret_cast<const float4*>(&P[(size_t)(C + v) * N + n]);
    float4 pl = *reinterpret_cast<const float4*>(&P[(size_t)(2 * C + v) * N + n]);
    float4 ri = *reinterpret_cast<const float4*>(&rinv[n]);
    float mean = st3[v * 2], inv = st3[v * 2 + 1];
    float4 fc = *reinterpret_cast<const float4*>(&Fc[(size_t)v * N + n]);
    float pmv[4] = {pm.x, pm.y, pm.z, pm.w};
    float phv[4] = {ph.x + pl.x, ph.y + pl.y, ph.z + pl.z, ph.w + pl.w};
    float riv[4] = {ri.x, ri.y, ri.z, ri.w};
    float fcv[4] = {fc.x, fc.y, fc.z, fc.w};
    float o[4];
#pragma unroll
    for (int q = 0; q < 4; ++q) {
        float M  = pmv[q] * riv[q];
        float S2 = phv[q] * riv[q];
        float var = fmaxf(S2 - M * M, 0.f) + EPSV;
        o[q] = sqrtf(var) * ((fcv[q] - mean) * inv) + M;
    }
    *reinterpret_cast<float4*>(&out[(size_t)v * N + n]) =
        make_float4(o[0], o[1], o[2], o[3]);
}

// ---------------------------------------------------------------------------
extern "C" void kernel_launch(void* const* d_in, const int* in_sizes, int n_in,
                              void* d_out, int out_size, void* d_ws, size_t ws_size,
                              hipStream_t stream)
{
    const float* F_c      = (const float*)d_in[0];
    const float* F_s      = (const float*)d_in[1];
    const float* F_c_prev = (const float*)d_in[2];
    const float* F_s_prev = (const float*)d_in[3];
    const float* Wf = (const float*)d_in[4];
    const float* bf_ = (const float*)d_in[5];
    const float* Wg = (const float*)d_in[6];
    const float* bg_ = (const float*)d_in[7];
    const float* Wh = (const float*)d_in[8];
    const float* bh_ = (const float*)d_in[9];
    float* out = (float*)d_out;

    // byte-offset workspace carve-up, 256B aligned regions
    char* base = (char*)d_ws;
    size_t off = 0;
    auto alloc = [&](size_t bytes) { void* p = base + off; off = (off + bytes + 255) & ~(size_t)255; return p; };
    float* stats = (float*)alloc(3 * C * 2 * 4);
    float* bpf   = (float*)alloc(C * 4);
    float* bpg   = (float*)alloc(C * 4);
    float* bph   = (float*)alloc(C * 4);
    float* rinv  = (float*)alloc(N * 4);
    unsigned short* Wsf = (unsigned short*)alloc((size_t)C * C2 * 2);   // 1 MB each
    unsigned short* Wsg = (unsigned short*)alloc((size_t)C * C2 * 2);
    unsigned short* Wsh = (unsigned short*)alloc((size_t)C * C2 * 2);
    // Region A (16.78 MB): Qs|Ks during conv+qtk; E rows [2048,4096) afterwards.
    char* Areg = (char*)alloc((size_t)2 * N * C2 * 2);
    unsigned short* Qs = (unsigned short*)Areg;
    unsigned short* Ks = (unsigned short*)(Areg + (size_t)N * C2 * 2);
    unsigned short* E1 = (unsigned short*)Areg;
    // Region B (33.55 MB): Xs0/1/2 during in_split+conv; L during qtk/softmax;
    // P during AV+epilogue.
    char* Breg = (char*)alloc((size_t)NC * N * 4);
    unsigned short* Xs0 = (unsigned short*)Breg;
    unsigned short* Xs1 = (unsigned short*)(Breg + (size_t)N * C2 * 2);
    unsigned short* Xs2 = (unsigned short*)(Breg + (size_t)2 * N * C2 * 2);
    float* Lb = (float*)Breg;
    float* Pb = (float*)Breg;
    unsigned short* Tb = (unsigned short*)alloc((size_t)3 * C * N * 2); // 12.58 MB
    unsigned short* E0 = (unsigned short*)alloc((size_t)NC * N * 2);    // 16.78 MB
    if (ws_size < off) return;  // insufficient scratch -> visible failure

    hipLaunchKernelGGL(stats_kernel, dim3(C, 3), dim3(256), 0, stream,
                       F_c_prev, F_s_prev, F_c, stats);
    hipLaunchKernelGGL(eff_weights_split, dim3(C, 3), dim3(256), 0, stream,
                       Wf, bf_, Wg, bg_, Wh, bh_, stats, Wsf, Wsg, Wsh, bpf, bpg, bph);

    for (int b = 0; b < B; ++b) {
        const float* Xq = F_c_prev + (size_t)b * C * N;
        const float* Xk = F_s_prev + (size_t)b * C * N;
        const float* Xv = F_s      + (size_t)b * C * N;

        hipLaunchKernelGGL(in_split_all, dim3(N / 64, C / 64, 3), dim3(256), 0, stream,
                           Xq, Xk, Xv, Xs0, Xs1, Xs2);
        hipLaunchKernelGGL(conv_all, dim3(N / 64, C / 128, 3), dim3(256), 0, stream,
                           Wsf, Wsg, Wsh, Xs0, Xs1, Xs2, bpf, bpg, bph, Qs, Ks, Tb);

        // chunk 0: logits -> E0
        hipLaunchKernelGGL(gemm_qtk_mfma, dim3(N / 64, NC / 128), dim3(256), 0, stream,
                           Qs, Ks, Lb, 0);
        hipLaunchKernelGGL(softmax_bf16, dim3(NC), dim3(256), 0, stream, Lb, E0, rinv, 0);
        // chunk 1: logits -> E1 (overlays dead Qs/Ks after qtk reads them)
        hipLaunchKernelGGL(gemm_qtk_mfma, dim3(N / 64, NC / 128), dim3(256), 0, stream,
                           Qs, Ks, Lb, NC);
        hipLaunchKernelGGL(softmax_bf16, dim3(NC), dim3(256), 0, stream, Lb, E1, rinv, NC);
        // merged AV over full N
        hipLaunchKernelGGL(gemm_av_mfma, dim3(N / 64, 3 * C / 128), dim3(256), 0, stream,
                           Tb, E0, E1, Pb);
        hipLaunchKernelGGL(av_epilogue, dim3((C * N / 4) / 256), dim3(256), 0, stream,
                           Pb, rinv, F_c + (size_t)b * C * N, stats + 2 * C * 2,
                           out + (size_t)b * C * N);
    }
}